// Round 11
// baseline (293.936 us; speedup 1.0000x reference)
//
#include <hip/hip_runtime.h>
#include <hip/hip_bf16.h>
#include <math.h>
#include <float.h>

// dims
constexpr int NQ = 64, NK = 256, SSZ = 64, D = 512, FF = 2048;
constexpr int PAIRS = NQ * NK;          // 16384
constexpr int ROWSX = 2 * PAIRS;        // 32768
constexpr int NX = (NQ + NK) * SSZ;     // 20480 rows of X = [tgt;mem]
constexpr int SBLK = 256;               // stats1 partial blocks (full chip)

typedef __bf16 bf16x8 __attribute__((ext_vector_type(8)));
typedef float floatx16 __attribute__((ext_vector_type(16)));

// async global->LDS, 16 B per lane; LDS dest = wave-uniform base + lane*16
__device__ __forceinline__ void gl2lds16(const unsigned short* g, unsigned short* l) {
    __builtin_amdgcn_global_load_lds(
        (const __attribute__((address_space(1))) unsigned int*)(g),
        (__attribute__((address_space(3))) unsigned int*)(l),
        16, 0, 0);
}

// Fragment layout for QKf: block (rg, kgrp) = 1 KB at ((rg*32 + kgrp)*1024):
//   lane l (16 B entry at l*16) holds row rg*32 + (l&31),
//   k elems kgrp*16 + (l>>5)*8 .. +7  == exactly the 32x32x16 A/B fragment.

// ---------------- K0: convert W1/W2 to bf16 + sigmoid(score_embed) ---------
// v12: X conversion moved into k_gemm1 (reg-staged from f32) -- saves 60 MB.
__global__ __launch_bounds__(256) void k_cvt(
        const float* __restrict__ W1, const float* __restrict__ W2,
        const float* __restrict__ se, const int* __restrict__ flag,
        __hip_bfloat16* __restrict__ W1b, __hip_bfloat16* __restrict__ W2b,
        float* __restrict__ sig) {
    constexpr int W4 = D * D / 4;          // W1 float4 count
    constexpr int V4 = FF * 64 / 4;        // W2 float4 count
    constexpr int S4 = SSZ * SSZ / 4;      // sig float4 count
    int idx = blockIdx.x * 256 + threadIdx.x;
    if (idx >= W4 + V4 + S4) return;
    if (idx >= W4 + V4) {                  // sigmoid branch
        int s = (idx - W4 - V4) * 4;
        float4 v = *reinterpret_cast<const float4*>(se + s);
        bool fl = (*flag) != 0;
        float4 o;
        o.x = fl ? 1.0f / (1.0f + expf(-v.x)) : 1.0f;
        o.y = fl ? 1.0f / (1.0f + expf(-v.y)) : 1.0f;
        o.z = fl ? 1.0f / (1.0f + expf(-v.z)) : 1.0f;
        o.w = fl ? 1.0f / (1.0f + expf(-v.w)) : 1.0f;
        *reinterpret_cast<float4*>(sig + s) = o;
        return;
    }
    const float* src;
    __hip_bfloat16* dst;
    if (idx < W4) { src = W1 + (size_t)idx * 4;        dst = W1b + (size_t)idx * 4; }
    else          { src = W2 + (size_t)(idx - W4) * 4; dst = W2b + (size_t)(idx - W4) * 4; }
    float4 v = *reinterpret_cast<const float4*>(src);
    union { __hip_bfloat16 h[4]; uint2 u; } o;
    o.h[0] = __float2bfloat16(v.x); o.h[1] = __float2bfloat16(v.y);
    o.h[2] = __float2bfloat16(v.z); o.h[3] = __float2bfloat16(v.w);
    *reinterpret_cast<uint2*>(dst) = o.u;
}

// ---------------- K1: MFMA GEMM1: QKf = frag(X @ W1^T + b1) ----------------
// v12: A-operand (X) reg-staged straight from f32 tgt/mem (cvt fused);
// B-operand (W1b) still async gl2lds. Waves 0-1 stage A, waves 2-3 stage B.
__global__ __launch_bounds__(256, 3) void k_gemm1_mfma(
        const float* __restrict__ tgt, const float* __restrict__ mem,
        const __hip_bfloat16* __restrict__ W1b, const float* __restrict__ b1,
        const int* __restrict__ flag, __hip_bfloat16* __restrict__ QKf) {
    __shared__ __attribute__((aligned(16))) unsigned short lds[2 * 128 * 64]; // 32 KB
    const unsigned short* Wu = reinterpret_cast<const unsigned short*>(W1b);
    unsigned short* Fu = reinterpret_cast<unsigned short*>(QKf);

    int tid = threadIdx.x;
    int bm = blockIdx.x >> 2, bn = blockIdx.x & 3;
    int m0 = bm * 128, n0 = bn * 128;

    // block's A source rows (each 128-row tile lies entirely in tgt or mem)
    const float* Arow = (m0 < NQ * SSZ) ? (tgt + (size_t)m0 * D)
                                        : (mem + (size_t)(m0 - NQ * SSZ) * D);

    if (!(*flag)) {
        // copy X rows (f32 -> bf16) into fragment layout (flag==0 path)
#pragma unroll
        for (int i = 0; i < 8; ++i) {
            int e = i * 256 + tid;          // 0..2047 entries of 16 B
            int fb = e >> 6;                // frag block 0..31
            int lp = e & 63;                // lane entry
            int rgl = fb >> 3, kgl = fb & 7;
            int row = rgl * 32 + (lp & 31); // within tile
            int col = n0 + kgl * 16 + (lp >> 5) * 8;
            const float* srcf = Arow + (size_t)row * D + col;
            float4 v0 = *reinterpret_cast<const float4*>(srcf);
            float4 v1 = *reinterpret_cast<const float4*>(srcf + 4);
            union { __hip_bfloat16 hh[8]; uint4 u; } o;
            o.hh[0] = __float2bfloat16(v0.x); o.hh[1] = __float2bfloat16(v0.y);
            o.hh[2] = __float2bfloat16(v0.z); o.hh[3] = __float2bfloat16(v0.w);
            o.hh[4] = __float2bfloat16(v1.x); o.hh[5] = __float2bfloat16(v1.y);
            o.hh[6] = __float2bfloat16(v1.z); o.hh[7] = __float2bfloat16(v1.w);
            size_t ofs = ((size_t)((m0 >> 5) + rgl) * 32 + (n0 >> 4) + kgl) * 512 + lp * 8;
            *reinterpret_cast<uint4*>(Fu + ofs) = o.u;
        }
        return;
    }

    int w = tid >> 6, l = tid & 63, h = l >> 5, c = l & 31;
    int wm = w >> 1, wn = w & 1;
    int chg = (l & 7) ^ (l >> 3);     // swizzled source chunk for this lane
    int cx = c & 7;
    floatx16 acc00 = {}, acc01 = {}, acc10 = {}, acc11 = {};

    for (int kb = 0; kb < D; kb += 64) {
        if (w < 2) {
            // A (X) staging: f32 load + cvt + ds_write, same swizzled layout
#pragma unroll
            for (int j = 0; j < 8; ++j) {
                int i = w * 8 + j;          // 0..15
                int rb = i * 8;
                int r = rb + (l >> 3);
                const float* src = Arow + (size_t)r * D + kb + chg * 8;
                float4 v0 = *reinterpret_cast<const float4*>(src);
                float4 v1 = *reinterpret_cast<const float4*>(src + 4);
                union { __hip_bfloat16 hh[8]; uint4 u; } o;
                o.hh[0] = __float2bfloat16(v0.x); o.hh[1] = __float2bfloat16(v0.y);
                o.hh[2] = __float2bfloat16(v0.z); o.hh[3] = __float2bfloat16(v0.w);
                o.hh[4] = __float2bfloat16(v1.x); o.hh[5] = __float2bfloat16(v1.y);
                o.hh[6] = __float2bfloat16(v1.z); o.hh[7] = __float2bfloat16(v1.w);
                *reinterpret_cast<uint4*>(lds + rb * 64 + l * 8) = o.u;
            }
        } else {
            // B (W1b) staging: async global->LDS as before
#pragma unroll
            for (int j = 0; j < 8; ++j) {
                int i = (w - 2) * 8 + j;    // 0..15
                int rb = i * 8;
                int r = rb + (l >> 3);
                gl2lds16(Wu + (size_t)(n0 + r) * D + kb + chg * 8,
                         lds + 8192 + rb * 64);
            }
        }
        __syncthreads();
        const unsigned short* pA = lds + (wm * 64) * 64;
        const unsigned short* pB = lds + 8192 + (wn * 64) * 64;
#pragma unroll
        for (int st = 0; st < 4; ++st) {
            int ko = ((st * 2 + h) ^ cx) * 8;
            bf16x8 a0 = *reinterpret_cast<const bf16x8*>(pA + c * 64 + ko);
            bf16x8 a1 = *reinterpret_cast<const bf16x8*>(pA + (32 + c) * 64 + ko);
            bf16x8 b0 = *reinterpret_cast<const bf16x8*>(pB + c * 64 + ko);
            bf16x8 b1v = *reinterpret_cast<const bf16x8*>(pB + (32 + c) * 64 + ko);
            acc00 = __builtin_amdgcn_mfma_f32_32x32x16_bf16(b0, a0, acc00, 0, 0, 0);
            acc01 = __builtin_amdgcn_mfma_f32_32x32x16_bf16(b0, a1, acc01, 0, 0, 0);
            acc10 = __builtin_amdgcn_mfma_f32_32x32x16_bf16(b1v, a0, acc10, 0, 0, 0);
            acc11 = __builtin_amdgcn_mfma_f32_32x32x16_bf16(b1v, a1, acc11, 0, 0, 0);
        }
        __syncthreads();
    }

#pragma unroll
    for (int ni = 0; ni < 2; ++ni) {
        int nb = n0 + wn * 64 + ni * 32;
#pragma unroll
        for (int mi = 0; mi < 2; ++mi) {
            const floatx16& A = ni ? (mi ? acc11 : acc10) : (mi ? acc01 : acc00);
            int mb = m0 + wm * 64 + mi * 32;
            size_t rgbase = ((size_t)(mb >> 5) * 32 + (nb >> 4)) * 512;
#pragma unroll
            for (int g = 0; g < 4; ++g) {
                float4 bia = *reinterpret_cast<const float4*>(&b1[nb + 8 * g + 4 * h]);
                union { __hip_bfloat16 hh[4]; uint2 u; } o;
                o.hh[0] = __float2bfloat16(A[4 * g + 0] + bia.x);
                o.hh[1] = __float2bfloat16(A[4 * g + 1] + bia.y);
                o.hh[2] = __float2bfloat16(A[4 * g + 2] + bia.z);
                o.hh[3] = __float2bfloat16(A[4 * g + 3] + bia.w);
                *reinterpret_cast<uint2*>(Fu + rgbase + (size_t)(g >> 1) * 512
                                          + (c + 32 * (g & 1)) * 8 + 4 * h) = o.u;
            }
        }
    }
}

// ---------------- K2: MFMA score einsum + sigmoid + dual max ---------------
// v7 structure (proven best, FROZEN) + qbase split: each dispatch covers 16
// qig values so per-dispatch time halves and other kernels surface in top-5.
__global__ __launch_bounds__(512, 2) void k_score_mfma(
        const __hip_bfloat16* __restrict__ QKf, const float* __restrict__ sig,
        float* __restrict__ xbuf, int qbase) {
    __shared__ __attribute__((aligned(16))) unsigned short lds[65536]; // 128KB Q
    const unsigned short* Fu = reinterpret_cast<const unsigned short*>(QKf);

    int tid = threadIdx.x;
    int w = tid >> 6, l = tid & 63, h = l >> 5, c = l & 31;
    int qig = qbase + (blockIdx.x >> 5), ktg = blockIdx.x & 31; // bid%8=ktg%8 -> XCD pin
    int kt = ktg * 8 + w;

    const unsigned short* Qg = Fu + (size_t)qig * 65536;
#pragma unroll
    for (int i = 0; i < 16; ++i) {
        int e = i * 512 + tid;          // 16-B entry index
        gl2lds16(Qg + e * 8, lds + e * 8);
    }

    const unsigned short* pK0 = Fu + (size_t)(128 + kt * 2) * 16384 + l * 8;
    const unsigned short* pK1 = pK0 + 16384;

    floatx16 acc[2][4] = {};
    bf16x8 ka0[2][4], ka1[2][4];     // [buf][st], rows sh=0 / sh=1
#pragma unroll
    for (int st = 0; st < 4; ++st) {
        ka0[0][st] = *reinterpret_cast<const bf16x8*>(pK0 + st * 512);
        ka1[0][st] = *reinterpret_cast<const bf16x8*>(pK1 + st * 512);
    }
    __syncthreads();   // Q staged (vmcnt drained); K step-0 complete

    const unsigned short* qlds = lds + l * 8;
#pragma unroll
    for (int kbi = 0; kbi < 8; ++kbi) {
        const int cur = kbi & 1, nxt = cur ^ 1;
        if (kbi < 7) {
            pK0 += 2048; pK1 += 2048;
#pragma unroll
            for (int st = 0; st < 4; ++st) {
                ka0[nxt][st] = *reinterpret_cast<const bf16x8*>(pK0 + st * 512);
                ka1[nxt][st] = *reinterpret_cast<const bf16x8*>(pK1 + st * 512);
            }
        }
#pragma unroll
        for (int g = 0; g < 4; ++g) {
            bf16x8 qb[4];
#pragma unroll
            for (int st = 0; st < 4; ++st)
                qb[st] = *reinterpret_cast<const bf16x8*>(qlds + (g * 32 + kbi * 4 + st) * 512);
            __builtin_amdgcn_s_setprio(1);
#pragma unroll
            for (int st = 0; st < 4; ++st) {
                acc[0][g] = __builtin_amdgcn_mfma_f32_32x32x16_bf16(ka0[cur][st], qb[st], acc[0][g], 0, 0, 0);
                acc[1][g] = __builtin_amdgcn_mfma_f32_32x32x16_bf16(ka1[cur][st], qb[st], acc[1][g], 0, 0, 0);
            }
            __builtin_amdgcn_s_setprio(0);
        }
    }

    const float* sigl = sig;   // 16 KB, L2/L1-hot, coalesced per-row reads

    int p0 = (qig * 2) * 256 + kt;   // pair for qi = 2*qig   (cols g=0,1)
    int p1 = p0 + 256;               // pair for qi = 2*qig+1 (cols g=2,3)
    float tmax[4] = {-FLT_MAX, -FLT_MAX, -FLT_MAX, -FLT_MAX};
#pragma unroll
    for (int sh = 0; sh < 2; ++sh) {
        float smA[16], smB[16];
#pragma unroll
        for (int r = 0; r < 16; ++r) {
            int srow = sh * 32 + (r & 3) + 8 * (r >> 2) + 4 * h;
            float s0 = sigl[srow * 64 + c];
            float s1 = sigl[srow * 64 + 32 + c];
            float v0 = acc[sh][0][r] * s0;
            float v1 = acc[sh][1][r] * s1;
            float v2 = acc[sh][2][r] * s0;
            float v3 = acc[sh][3][r] * s1;
            tmax[0] = fmaxf(tmax[0], v0);
            tmax[1] = fmaxf(tmax[1], v1);
            tmax[2] = fmaxf(tmax[2], v2);
            tmax[3] = fmaxf(tmax[3], v3);
            smA[r] = fmaxf(v0, v1);
            smB[r] = fmaxf(v2, v3);
        }
#pragma unroll
        for (int stage = 1; stage < 32; stage <<= 1)
#pragma unroll
            for (int r = 0; r < 16; ++r) {
                smA[r] = fmaxf(smA[r], __shfl_xor(smA[r], stage, 64));
                smB[r] = fmaxf(smB[r], __shfl_xor(smB[r], stage, 64));
            }
        if (c == 0) {
#pragma unroll
            for (int r = 0; r < 16; ++r) {
                int srow = sh * 32 + (r & 3) + 8 * (r >> 2) + 4 * h;
                xbuf[(size_t)(2 * p0 + 1) * 64 + srow] = smA[r];
                xbuf[(size_t)(2 * p1 + 1) * 64 + srow] = smB[r];
            }
        }
    }
#pragma unroll
    for (int g = 0; g < 4; ++g)
        tmax[g] = fmaxf(tmax[g], __shfl_xor(tmax[g], 32, 64));
    if (h == 0) {
        xbuf[(size_t)(2 * p0) * 64 + c] = tmax[0];
        xbuf[(size_t)(2 * p0) * 64 + 32 + c] = tmax[1];
        xbuf[(size_t)(2 * p1) * 64 + c] = tmax[2];
        xbuf[(size_t)(2 * p1) * 64 + 32 + c] = tmax[3];
    }
}

// ---------------- K3: row stats partials (NO atomics) ----------------------
__global__ __launch_bounds__(256) void k_stats1(const float* __restrict__ xbuf,
        float* __restrict__ S1p, float* __restrict__ S2p) {
    __shared__ float xr[8][64];   // 2 KB
    int tid = threadIdx.x;
    int row0 = blockIdx.x * 128;
    float acc[16] = {};
    float s1 = 0.f;
    int a = tid >> 2;             // constant per thread
    int bbase = (tid & 3) * 16;
    int lr = tid >> 5, lc = (tid & 31) * 2;
    for (int it = 0; it < 16; ++it) {
        int r = row0 + it * 8;
        *reinterpret_cast<float2*>(&xr[lr][lc]) =
            *reinterpret_cast<const float2*>(&xbuf[(size_t)(r + lr) * 64 + lc]);
        __syncthreads();
        float xa[8];
#pragma unroll
        for (int j = 0; j < 8; ++j) xa[j] = xr[j][a];
#pragma unroll
        for (int j = 0; j < 8; ++j) {
            const float4* pb = reinterpret_cast<const float4*>(&xr[j][bbase]);
            float4 b0 = pb[0], b1 = pb[1], b2 = pb[2], b3 = pb[3];
            acc[0] += xa[j] * b0.x;  acc[1] += xa[j] * b0.y;
            acc[2] += xa[j] * b0.z;  acc[3] += xa[j] * b0.w;
            acc[4] += xa[j] * b1.x;  acc[5] += xa[j] * b1.y;
            acc[6] += xa[j] * b1.z;  acc[7] += xa[j] * b1.w;
            acc[8] += xa[j] * b2.x;  acc[9] += xa[j] * b2.y;
            acc[10] += xa[j] * b2.z; acc[11] += xa[j] * b2.w;
            acc[12] += xa[j] * b3.x; acc[13] += xa[j] * b3.y;
            acc[14] += xa[j] * b3.z; acc[15] += xa[j] * b3.w;
        }
        if (tid < 64) {
#pragma unroll
            for (int j = 0; j < 8; ++j) s1 += xr[j][tid];
        }
        __syncthreads();
    }
    float* dst = S2p + (size_t)blockIdx.x * 4096 + tid * 16;
#pragma unroll
    for (int e = 0; e < 16; e += 4)
        *reinterpret_cast<float4*>(dst + e) = make_float4(acc[e], acc[e+1], acc[e+2], acc[e+3]);
    if (tid < 64) S1p[blockIdx.x * 64 + tid] = s1;
}

// ---------------- K3b: reduce partials -> S2f[4096], S1f[64] ---------------
__global__ __launch_bounds__(256) void k_red(const float* __restrict__ S1p,
        const float* __restrict__ S2p, float* __restrict__ S1f,
        float* __restrict__ S2f) {
    __shared__ double part[4][64];
    __shared__ double p1s[4][64];
    int tid = threadIdx.x;
    int il = tid & 63, bq = tid >> 6;
    int idx = blockIdx.x * 64 + il;
    const float* b2 = S2p + (size_t)(bq * 64) * 4096 + idx;
    double a0 = 0, a1 = 0, a2 = 0, a3 = 0, a4 = 0, a5 = 0, a6 = 0, a7 = 0;
    for (int b = 0; b < 64; b += 8) {
        a0 += (double)b2[(size_t)(b + 0) * 4096];
        a1 += (double)b2[(size_t)(b + 1) * 4096];
        a2 += (double)b2[(size_t)(b + 2) * 4096];
        a3 += (double)b2[(size_t)(b + 3) * 4096];
        a4 += (double)b2[(size_t)(b + 4) * 4096];
        a5 += (double)b2[(size_t)(b + 5) * 4096];
        a6 += (double)b2[(size_t)(b + 6) * 4096];
        a7 += (double)b2[(size_t)(b + 7) * 4096];
    }
    part[bq][il] = ((a0 + a1) + (a2 + a3)) + ((a4 + a5) + (a6 + a7));
    if (blockIdx.x == 0) {
        const float* b1p = S1p + (size_t)(bq * 64) * 64 + il;
        double c0 = 0, c1 = 0, c2 = 0, c3 = 0;
        for (int b = 0; b < 64; b += 4) {
            c0 += (double)b1p[(size_t)(b + 0) * 64];
            c1 += (double)b1p[(size_t)(b + 1) * 64];
            c2 += (double)b1p[(size_t)(b + 2) * 64];
            c3 += (double)b1p[(size_t)(b + 3) * 64];
        }
        p1s[bq][il] = (c0 + c1) + (c2 + c3);
    }
    __syncthreads();
    if (tid < 64) {
        S2f[blockIdx.x * 64 + tid] =
            (float)(part[0][tid] + part[1][tid] + part[2][tid] + part[3][tid]);
        if (blockIdx.x == 0)
            S1f[tid] = (float)(p1s[0][tid] + p1s[1][tid] + p1s[2][tid] + p1s[3][tid]);
    }
}

// ---------------- K5: BN2 constants; BN1 stats inline; S2f in padded LDS ---
__global__ __launch_bounds__(256) void k_bn2(
        const float* __restrict__ S1f, const float* __restrict__ S2f,
        const __hip_bfloat16* __restrict__ W2b,
        const float* __restrict__ g1, const float* __restrict__ be1,
        const float* __restrict__ g2, const float* __restrict__ be2,
        float* __restrict__ alpha, float* __restrict__ beta) {
    __shared__ float S2c[64 * 65];
    __shared__ float mb[64];
    __shared__ float scal[3];   // sc2, m1, scaled
    int tid = threadIdx.x;
    const float Rinvf = 1.0f / (float)ROWSX;
#pragma unroll
    for (int i = 0; i < 16; ++i) {
        int idx = i * 256 + tid;
        S2c[(idx >> 6) * 65 + (idx & 63)] = S2f[idx];
    }
    if (tid < 64) {
        double ss = (double)S1f[tid];
        double sq = (double)S2f[tid * 65];
#pragma unroll
        for (int off = 32; off; off >>= 1) {
            ss += __shfl_down(ss, off);
            sq += __shfl_down(sq, off);
        }
        if (tid == 0) {
            const double Nall = (double)ROWSX * 64.0;
            double m1 = ss / Nall;
            double var1 = sq / Nall - m1 * m1;
            double scaled = (double)g1[0] / sqrt(var1 + 1e-5);
            scal[0] = (float)(scaled * scaled);
            scal[1] = (float)m1;
            scal[2] = (float)scaled;
        }
        mb[tid] = S1f[tid] * Rinvf;
    }
    __syncthreads();
    int w = tid >> 6;
    int j = tid & 63;
    int f = blockIdx.x * 4 + w;
    float wj = __bfloat162float(W2b[(size_t)f * 64 + j]);
    float mj = mb[j];
    float t1 = 0.f;
    for (int b = 0; b < 64; ++b)
        t1 += (S2c[j * 65 + b] * Rinvf - mj * mb[b]) * __bfloat162float(W2b[(size_t)f * 64 + b]);
    float vc = wj * t1 * scal[0];
    float xbj = (mj - scal[1]) * scal[2] + be1[0];
    float mc = wj * xbj;
#pragma unroll
    for (int off = 32; off; off >>= 1) {
        vc += __shfl_down(vc, off);
        mc += __shfl_down(mc, off);
    }
    if (j == 0) {
        float t2 = g2[f] * rsqrtf(vc + 1e-5f);
        alpha[f] = t2;
        beta[f] = -t2 * mc + be2[f];
    }
}

// ---------------- K6: MFMA MLP; 4-way feature split for occupancy ----------
__global__ __launch_bounds__(256, 4) void k_mlp_mfma(
        const float* __restrict__ xbuf, const float* __restrict__ S1f,
        const float* __restrict__ S2f, const float* __restrict__ g1,
        const float* __restrict__ be1, const __hip_bfloat16* __restrict__ W2b,
        const float* __restrict__ alpha, const float* __restrict__ beta,
        const float* __restrict__ W3, const float* __restrict__ b3,
        float* __restrict__ z4) {
    constexpr int LDR = 72;
    __shared__ __attribute__((aligned(16))) unsigned short Xs[128 * LDR];
    __shared__ __attribute__((aligned(16))) unsigned short Ws[128 * LDR];
    __shared__ float abw[3 * 128];
    __shared__ float scl[2];
    const unsigned short* W2u = reinterpret_cast<const unsigned short*>(W2b);
    int tid = threadIdx.x;
    int w = tid >> 6, l = tid & 63, h = l >> 5, c = l & 31;
    int rb = blockIdx.x >> 2, q = blockIdx.x & 3;
    int r0 = rb * 128;

    if (tid < 64) {
        double ss = (double)S1f[tid];
        double sq = (double)S2f[tid * 65];
#pragma unroll
        for (int off = 32; off; off >>= 1) {
            ss += __shfl_down(ss, off);
            sq += __shfl_down(sq, off);
        }
        if (tid == 0) {
            const double Nall = (double)ROWSX * 64.0;
            double m1 = ss / Nall;
            double var1 = sq / Nall - m1 * m1;
            scl[0] = (float)m1;
            scl[1] = (float)((double)g1[0] / sqrt(var1 + 1e-5));
        }
    }
    __syncthreads();
    float m1 = scl[0], sc = scl[1], sh = be1[0];

#pragma unroll
    for (int i = 0; i < 4; ++i) {
        int id = i * 256 + tid;
        int row = id >> 3, cg = id & 7;
        const float* src = xbuf + (size_t)(r0 + row) * 64 + cg * 8;
        float4 v0 = *reinterpret_cast<const float4*>(src);
        float4 v1 = *reinterpret_cast<const float4*>(src + 4);
        union { __hip_bfloat16 hh[8]; uint4 u; } o;
        o.hh[0] = __float2bfloat16((v0.x - m1) * sc + sh);
        o.hh[1] = __float2bfloat16((v0.y - m1) * sc + sh);
        o.hh[2] = __float2bfloat16((v0.z - m1) * sc + sh);
        o.hh[3] = __float2bfloat16((v0.w - m1) * sc + sh);
        o.hh[4] = __float2bfloat16((v1.x - m1) * sc + sh);
        o.hh[5] = __float2bfloat16((v1.y - m1) * sc + sh);
        o.hh[6] = __float2bfloat16((v1.z - m1) * sc + sh);
        o.hh[7] = __float2bfloat16((v1.w - m1) * sc + sh);
        *reinterpret_cast<uint4*>(&Xs[row * LDR + cg * 8]) = o.u;
    }

    float zacc[16] = {};
    for (int fci = 0; fci < 4; ++fci) {
        int fc = q * 4 + fci;
#pragma unroll
        for (int i = 0; i < 4; ++i) {
            int id = i * 256 + tid;
            int row = id >> 3, cg = id & 7;
            uint4 v = *reinterpret_cast<const uint4*>(W2u + (size_t)(fc * 128 + row) * 64 + cg * 8);
            *reinterpret_cast<uint4*>(&Ws[row * LDR + cg * 8]) = v;
        }
        if (tid < 128) {
            int f = fc * 128 + tid;
            abw[tid] = alpha[f];
            abw[128 + tid] = beta[f];
            abw[256 + tid] = W3[f];
        }
        __syncthreads();
        bf16x8 a[4];
#pragma unroll
        for (int st = 0; st < 4; ++st)
            a[st] = *reinterpret_cast<const bf16x8*>(&Xs[(w * 32 + c) * LDR + st * 16 + h * 8]);
#pragma unroll
        for (int nq = 0; nq < 4; ++nq) {
            floatx16 u = {};
#pragma unroll
            for (int st = 0; st < 4; ++st) {
                bf16x8 b = *reinterpret_cast<const bf16x8*>(&Ws[(nq * 32 + c) * LDR + st * 16 + h * 8]);
                u = __builtin_amdgcn_mfma_f32_32x32x16_bf16(a[st], b, u, 0, 0, 0);
            }
            float al = abw[nq * 32 + c];
            float bt = abw[128 + nq * 32 + c];
            float w3 = abw[256 + nq * 32 + c];
#pragma unroll
            for (int r = 0; r < 16; ++r)
                zacc[r] += fmaxf(al * u[r] + bt, 0.f) * w3;
        }
        __syncthreads();
    }
#pragma unroll
    for (int stage = 1; stage < 32; stage <<= 1)
#pragma unroll
        for (int r = 0; r < 16; ++r)
            zacc[r] += __shfl_xor(zacc[r], stage, 64);
    if (c == 0) {
        float bb = (q == 0) ? b3[0] : 0.f;
#pragma unroll
        for (int r = 0; r < 16; ++r) {
            int row = r0 + w * 32 + (r & 3) + 8 * (r >> 2) + 4 * h;
            z4[(size_t)q * ROWSX + row] = zacc[r] + bb;
        }
    }
}

// ---------------- K7: pair-sum (4 partials) + BN3 stats --------------------
__global__ __launch_bounds__(256) void k_pair(const float* __restrict__ z4,
        float* __restrict__ v, double* __restrict__ sums3) {
    int i = blockIdx.x * 256 + threadIdx.x;
    float val = 0.f;
#pragma unroll
    for (int q = 0; q < 4; ++q)
        val += z4[(size_t)q * ROWSX + 2 * i] + z4[(size_t)q * ROWSX + 2 * i + 1];
    v[i] = val;
    float s = val, ss = val * val;
#pragma unroll
    for (int off = 32; off; off >>= 1) {
        s += __shfl_down(s, off);
        ss += __shfl_down(ss, off);
    }
    __shared__ float bs[4], bss[4];
    int lane = threadIdx.x & 63, w = threadIdx.x >> 6;
    if (lane == 0) { bs[w] = s; bss[w] = ss; }
    __syncthreads();
    if (threadIdx.x == 0) {
        atomicAdd(&sums3[0], (double)(bs[0] + bs[1] + bs[2] + bs[3]));
        atomicAdd(&sums3[1], (double)(bss[0] + bss[1] + bss[2] + bss[3]));
    }
}

// ---------------- K9: BN3 finalize + write output --------------------------
__global__ __launch_bounds__(256) void k_out(const float* __restrict__ v,
        const double* __restrict__ sums3, const float* __restrict__ g3,
        const float* __restrict__ be3, float* __restrict__ out) {
    double m = sums3[0] / (double)PAIRS;
    double var = sums3[1] / (double)PAIRS - m * m;
    float mm = (float)m;
    float inv = (float)((double)g3[0] / sqrt(var + 1e-5));
    int i = blockIdx.x * 256 + threadIdx.x;
    if (i < PAIRS) out[i] = (v[i] - mm) * inv + be3[0];
}

extern "C" void kernel_launch(void* const* d_in, const int* in_sizes, int n_in,
                              void* d_out, int out_size, void* d_ws, size_t ws_size,
                              hipStream_t stream) {
    (void)in_sizes; (void)n_in; (void)out_size; (void)ws_size;
    const float* tgt = (const float*)d_in[0];
    const float* mem = (const float*)d_in[1];
    const float* W1  = (const float*)d_in[2];
    const float* b1  = (const float*)d_in[3];
    const float* se  = (const float*)d_in[4];
    const float* W2  = (const float*)d_in[5];
    const float* b2  = (const float*)d_in[6];
    const float* W3  = (const float*)d_in[7];
    const float* b3  = (const float*)d_in[8];
    const float* g1  = (const float*)d_in[9];
    const float* be1 = (const float*)d_in[10];
    const float* g2  = (const float*)d_in[11];
    const float* be2 = (const float*)d_in[12];
    const float* g3  = (const float*)d_in[13];
    const float* be3 = (const float*)d_in[14];
    const int*  flag = (const int*)d_in[15];
    (void)b2;  // cancels analytically through BN2's mean-subtract
    float* out = (float*)d_out;

    char* ws = (char*)d_ws;
    size_t off = 0;
    auto alloc = [&](size_t bytes) -> void* {
        void* p = ws + off;
        off = (off + bytes + 255) & ~(size_t)255;
        return p;
    };
    float* sig   = (float*)alloc((size_t)SSZ * SSZ * 4);
    __hip_bfloat16* W1b = (__hip_bfloat16*)alloc((size_t)D * D * 2);    // 0.5 MB
    __hip_bfloat16* W2b = (__hip_bfloat16*)alloc((size_t)FF * 64 * 2);  // 0.25 MB
    __hip_bfloat16* QKf = (__hip_bfloat16*)alloc((size_t)NX * D * 2);   // 21 MB (fragment layout)
    float* xbuf  = (float*)alloc((size_t)ROWSX * 64 * 4);               // 8 MB
    float* z4    = (float*)alloc((size_t)4 * ROWSX * 4);                // 0.5 MB
    float* v     = (float*)alloc((size_t)PAIRS * 4);
    float* alpha = (float*)alloc((size_t)FF * 4);
    float* beta  = (float*)alloc((size_t)FF * 4);
    float* S1p   = (float*)alloc((size_t)SBLK * 64 * 4);
    float* S2p   = (float*)alloc((size_t)SBLK * 4096 * 4);   // 4 MB
    float* S1f   = (float*)alloc(64 * 4);
    float* S2f   = (float*)alloc(4096 * 4);
    size_t statsStart = off;
    double* sums3 = (double*)alloc(2 * 8);
    size_t statsEnd = off;

    hipMemsetAsync(ws + statsStart, 0, statsEnd - statsStart, stream);

    constexpr int CVT4 = (D * D + FF * 64 + SSZ * SSZ) / 4;
    k_cvt<<<(CVT4 + 255) / 256, 256, 0, stream>>>(W1, W2, se, flag, W1b, W2b, sig);
    k_gemm1_mfma<<<(NX / 128) * (D / 128), 256, 0, stream>>>(tgt, mem, W1b, b1, flag, QKf);
    k_score_mfma<<<(NQ / 4) * (NK / 8), 512, 0, stream>>>(QKf, sig, xbuf, 0);
    k_score_mfma<<<(NQ / 4) * (NK / 8), 512, 0, stream>>>(QKf, sig, xbuf, 16);
    k_stats1<<<SBLK, 256, 0, stream>>>(xbuf, S1p, S2p);
    k_red<<<64, 256, 0, stream>>>(S1p, S2p, S1f, S2f);
    k_bn2<<<FF / 4, 256, 0, stream>>>(S1f, S2f, W2b, g1, be1, g2, be2, alpha, beta);
    k_mlp_mfma<<<(ROWSX / 128) * 4, 256, 0, stream>>>(xbuf, S1f, S2f, g1, be1, W2b,
                                                      alpha, beta, W3, b3, z4);
    k_pair<<<PAIRS / 256, 256, 0, stream>>>(z4, v, sums3);
    k_out<<<PAIRS / 256, 256, 0, stream>>>(v, sums3, g3, be3, out);
}

// Round 12
// 281.923 us; speedup vs baseline: 1.0426x; 1.0426x over previous
//
#include <hip/hip_runtime.h>
#include <hip/hip_bf16.h>
#include <math.h>
#include <float.h>

// dims
constexpr int NQ = 64, NK = 256, SSZ = 64, D = 512, FF = 2048;
constexpr int PAIRS = NQ * NK;          // 16384
constexpr int ROWSX = 2 * PAIRS;        // 32768
constexpr int NX = (NQ + NK) * SSZ;     // 20480 rows of X = [tgt;mem]
constexpr int SBLK = 256;               // stats1 partial blocks (full chip)

typedef __bf16 bf16x8 __attribute__((ext_vector_type(8)));
typedef float floatx16 __attribute__((ext_vector_type(16)));

// async global->LDS, 16 B per lane; LDS dest = wave-uniform base + lane*16
__device__ __forceinline__ void gl2lds16(const unsigned short* g, unsigned short* l) {
    __builtin_amdgcn_global_load_lds(
        (const __attribute__((address_space(1))) unsigned int*)(g),
        (__attribute__((address_space(3))) unsigned int*)(l),
        16, 0, 0);
}

// Fragment layout for QKf: block (rg, kgrp) = 1 KB at ((rg*32 + kgrp)*1024):
//   lane l (16 B entry at l*16) holds row rg*32 + (l&31),
//   k elems kgrp*16 + (l>>5)*8 .. +7  == exactly the 32x32x16 A/B fragment.

// ---------------- K0: convert W1/W2 to bf16 + sigmoid(score_embed) ---------
__global__ __launch_bounds__(256) void k_cvt(
        const float* __restrict__ W1, const float* __restrict__ W2,
        const float* __restrict__ se, const int* __restrict__ flag,
        __hip_bfloat16* __restrict__ W1b, __hip_bfloat16* __restrict__ W2b,
        float* __restrict__ sig) {
    constexpr int W4 = D * D / 4;          // W1 float4 count
    constexpr int V4 = FF * 64 / 4;        // W2 float4 count
    constexpr int S4 = SSZ * SSZ / 4;      // sig float4 count
    int idx = blockIdx.x * 256 + threadIdx.x;
    if (idx >= W4 + V4 + S4) return;
    if (idx >= W4 + V4) {                  // sigmoid branch
        int s = (idx - W4 - V4) * 4;
        float4 v = *reinterpret_cast<const float4*>(se + s);
        bool fl = (*flag) != 0;
        float4 o;
        o.x = fl ? 1.0f / (1.0f + expf(-v.x)) : 1.0f;
        o.y = fl ? 1.0f / (1.0f + expf(-v.y)) : 1.0f;
        o.z = fl ? 1.0f / (1.0f + expf(-v.z)) : 1.0f;
        o.w = fl ? 1.0f / (1.0f + expf(-v.w)) : 1.0f;
        *reinterpret_cast<float4*>(sig + s) = o;
        return;
    }
    const float* src;
    __hip_bfloat16* dst;
    if (idx < W4) { src = W1 + (size_t)idx * 4;        dst = W1b + (size_t)idx * 4; }
    else          { src = W2 + (size_t)(idx - W4) * 4; dst = W2b + (size_t)(idx - W4) * 4; }
    float4 v = *reinterpret_cast<const float4*>(src);
    union { __hip_bfloat16 h[4]; uint2 u; } o;
    o.h[0] = __float2bfloat16(v.x); o.h[1] = __float2bfloat16(v.y);
    o.h[2] = __float2bfloat16(v.z); o.h[3] = __float2bfloat16(v.w);
    *reinterpret_cast<uint2*>(dst) = o.u;
}

// ---------------- K1: MFMA GEMM1: QKf = frag(X @ W1^T + b1) ----------------
// v13: cvt-fused A staging BALANCED across all 4 waves (4 A-chunks with
// f32->bf16 cvt + 4 async B-chunks each); B gl2lds issued first so the async
// loads fly under the A cvt work. Staging critical path halves vs v12.
__global__ __launch_bounds__(256, 3) void k_gemm1_mfma(
        const float* __restrict__ tgt, const float* __restrict__ mem,
        const __hip_bfloat16* __restrict__ W1b, const float* __restrict__ b1,
        const int* __restrict__ flag, __hip_bfloat16* __restrict__ QKf) {
    __shared__ __attribute__((aligned(16))) unsigned short lds[2 * 128 * 64]; // 32 KB
    const unsigned short* Wu = reinterpret_cast<const unsigned short*>(W1b);
    unsigned short* Fu = reinterpret_cast<unsigned short*>(QKf);

    int tid = threadIdx.x;
    int bm = blockIdx.x >> 2, bn = blockIdx.x & 3;
    int m0 = bm * 128, n0 = bn * 128;

    // block's A source rows (each 128-row tile lies entirely in tgt or mem)
    const float* Arow = (m0 < NQ * SSZ) ? (tgt + (size_t)m0 * D)
                                        : (mem + (size_t)(m0 - NQ * SSZ) * D);

    if (!(*flag)) {
        // copy X rows (f32 -> bf16) into fragment layout (flag==0 path)
#pragma unroll
        for (int i = 0; i < 8; ++i) {
            int e = i * 256 + tid;          // 0..2047 entries of 16 B
            int fb = e >> 6;                // frag block 0..31
            int lp = e & 63;                // lane entry
            int rgl = fb >> 3, kgl = fb & 7;
            int row = rgl * 32 + (lp & 31); // within tile
            int col = n0 + kgl * 16 + (lp >> 5) * 8;
            const float* srcf = Arow + (size_t)row * D + col;
            float4 v0 = *reinterpret_cast<const float4*>(srcf);
            float4 v1 = *reinterpret_cast<const float4*>(srcf + 4);
            union { __hip_bfloat16 hh[8]; uint4 u; } o;
            o.hh[0] = __float2bfloat16(v0.x); o.hh[1] = __float2bfloat16(v0.y);
            o.hh[2] = __float2bfloat16(v0.z); o.hh[3] = __float2bfloat16(v0.w);
            o.hh[4] = __float2bfloat16(v1.x); o.hh[5] = __float2bfloat16(v1.y);
            o.hh[6] = __float2bfloat16(v1.z); o.hh[7] = __float2bfloat16(v1.w);
            size_t ofs = ((size_t)((m0 >> 5) + rgl) * 32 + (n0 >> 4) + kgl) * 512 + lp * 8;
            *reinterpret_cast<uint4*>(Fu + ofs) = o.u;
        }
        return;
    }

    int w = tid >> 6, l = tid & 63, h = l >> 5, c = l & 31;
    int wm = w >> 1, wn = w & 1;
    int chg = (l & 7) ^ (l >> 3);     // swizzled source chunk for this lane
    int cx = c & 7;
    floatx16 acc00 = {}, acc01 = {}, acc10 = {}, acc11 = {};

    for (int kb = 0; kb < D; kb += 64) {
        // B (W1b): 4 async gl2lds per wave, issued first
#pragma unroll
        for (int j = 0; j < 4; ++j) {
            int i = w * 4 + j;              // 0..15
            int rb = i * 8;
            int r = rb + (l >> 3);
            gl2lds16(Wu + (size_t)(n0 + r) * D + kb + chg * 8,
                     lds + 8192 + rb * 64);
        }
        // A (X): 4 chunks per wave, f32 load + cvt + ds_write (swizzled)
#pragma unroll
        for (int j = 0; j < 4; ++j) {
            int i = w * 4 + j;              // 0..15
            int rb = i * 8;
            int r = rb + (l >> 3);
            const float* src = Arow + (size_t)r * D + kb + chg * 8;
            float4 v0 = *reinterpret_cast<const float4*>(src);
            float4 v1 = *reinterpret_cast<const float4*>(src + 4);
            union { __hip_bfloat16 hh[8]; uint4 u; } o;
            o.hh[0] = __float2bfloat16(v0.x); o.hh[1] = __float2bfloat16(v0.y);
            o.hh[2] = __float2bfloat16(v0.z); o.hh[3] = __float2bfloat16(v0.w);
            o.hh[4] = __float2bfloat16(v1.x); o.hh[5] = __float2bfloat16(v1.y);
            o.hh[6] = __float2bfloat16(v1.z); o.hh[7] = __float2bfloat16(v1.w);
            *reinterpret_cast<uint4*>(lds + rb * 64 + l * 8) = o.u;
        }
        __syncthreads();
        const unsigned short* pA = lds + (wm * 64) * 64;
        const unsigned short* pB = lds + 8192 + (wn * 64) * 64;
#pragma unroll
        for (int st = 0; st < 4; ++st) {
            int ko = ((st * 2 + h) ^ cx) * 8;
            bf16x8 a0 = *reinterpret_cast<const bf16x8*>(pA + c * 64 + ko);
            bf16x8 a1 = *reinterpret_cast<const bf16x8*>(pA + (32 + c) * 64 + ko);
            bf16x8 b0 = *reinterpret_cast<const bf16x8*>(pB + c * 64 + ko);
            bf16x8 b1v = *reinterpret_cast<const bf16x8*>(pB + (32 + c) * 64 + ko);
            acc00 = __builtin_amdgcn_mfma_f32_32x32x16_bf16(b0, a0, acc00, 0, 0, 0);
            acc01 = __builtin_amdgcn_mfma_f32_32x32x16_bf16(b0, a1, acc01, 0, 0, 0);
            acc10 = __builtin_amdgcn_mfma_f32_32x32x16_bf16(b1v, a0, acc10, 0, 0, 0);
            acc11 = __builtin_amdgcn_mfma_f32_32x32x16_bf16(b1v, a1, acc11, 0, 0, 0);
        }
        __syncthreads();
    }

#pragma unroll
    for (int ni = 0; ni < 2; ++ni) {
        int nb = n0 + wn * 64 + ni * 32;
#pragma unroll
        for (int mi = 0; mi < 2; ++mi) {
            const floatx16& A = ni ? (mi ? acc11 : acc10) : (mi ? acc01 : acc00);
            int mb = m0 + wm * 64 + mi * 32;
            size_t rgbase = ((size_t)(mb >> 5) * 32 + (nb >> 4)) * 512;
#pragma unroll
            for (int g = 0; g < 4; ++g) {
                float4 bia = *reinterpret_cast<const float4*>(&b1[nb + 8 * g + 4 * h]);
                union { __hip_bfloat16 hh[4]; uint2 u; } o;
                o.hh[0] = __float2bfloat16(A[4 * g + 0] + bia.x);
                o.hh[1] = __float2bfloat16(A[4 * g + 1] + bia.y);
                o.hh[2] = __float2bfloat16(A[4 * g + 2] + bia.z);
                o.hh[3] = __float2bfloat16(A[4 * g + 3] + bia.w);
                *reinterpret_cast<uint2*>(Fu + rgbase + (size_t)(g >> 1) * 512
                                          + (c + 32 * (g & 1)) * 8 + 4 * h) = o.u;
            }
        }
    }
}

// ---------------- K2: MFMA score einsum + sigmoid + dual max ---------------
// v7 structure (proven best, FROZEN; single 1024-block dispatch restored).
__global__ __launch_bounds__(512, 2) void k_score_mfma(
        const __hip_bfloat16* __restrict__ QKf, const float* __restrict__ sig,
        float* __restrict__ xbuf) {
    __shared__ __attribute__((aligned(16))) unsigned short lds[65536]; // 128KB Q
    const unsigned short* Fu = reinterpret_cast<const unsigned short*>(QKf);

    int tid = threadIdx.x;
    int w = tid >> 6, l = tid & 63, h = l >> 5, c = l & 31;
    int qig = blockIdx.x >> 5, ktg = blockIdx.x & 31;  // bid%8 = ktg%8 -> XCD-pinned K
    int kt = ktg * 8 + w;

    const unsigned short* Qg = Fu + (size_t)qig * 65536;
#pragma unroll
    for (int i = 0; i < 16; ++i) {
        int e = i * 512 + tid;          // 16-B entry index
        gl2lds16(Qg + e * 8, lds + e * 8);
    }

    const unsigned short* pK0 = Fu + (size_t)(128 + kt * 2) * 16384 + l * 8;
    const unsigned short* pK1 = pK0 + 16384;

    floatx16 acc[2][4] = {};
    bf16x8 ka0[2][4], ka1[2][4];     // [buf][st], rows sh=0 / sh=1
#pragma unroll
    for (int st = 0; st < 4; ++st) {
        ka0[0][st] = *reinterpret_cast<const bf16x8*>(pK0 + st * 512);
        ka1[0][st] = *reinterpret_cast<const bf16x8*>(pK1 + st * 512);
    }
    __syncthreads();   // Q staged (vmcnt drained); K step-0 complete

    const unsigned short* qlds = lds + l * 8;
#pragma unroll
    for (int kbi = 0; kbi < 8; ++kbi) {
        const int cur = kbi & 1, nxt = cur ^ 1;
        if (kbi < 7) {
            pK0 += 2048; pK1 += 2048;
#pragma unroll
            for (int st = 0; st < 4; ++st) {
                ka0[nxt][st] = *reinterpret_cast<const bf16x8*>(pK0 + st * 512);
                ka1[nxt][st] = *reinterpret_cast<const bf16x8*>(pK1 + st * 512);
            }
        }
#pragma unroll
        for (int g = 0; g < 4; ++g) {
            bf16x8 qb[4];
#pragma unroll
            for (int st = 0; st < 4; ++st)
                qb[st] = *reinterpret_cast<const bf16x8*>(qlds + (g * 32 + kbi * 4 + st) * 512);
            __builtin_amdgcn_s_setprio(1);
#pragma unroll
            for (int st = 0; st < 4; ++st) {
                acc[0][g] = __builtin_amdgcn_mfma_f32_32x32x16_bf16(ka0[cur][st], qb[st], acc[0][g], 0, 0, 0);
                acc[1][g] = __builtin_amdgcn_mfma_f32_32x32x16_bf16(ka1[cur][st], qb[st], acc[1][g], 0, 0, 0);
            }
            __builtin_amdgcn_s_setprio(0);
        }
    }

    const float* sigl = sig;   // 16 KB, L2/L1-hot, coalesced per-row reads

    int p0 = (qig * 2) * 256 + kt;   // pair for qi = 2*qig   (cols g=0,1)
    int p1 = p0 + 256;               // pair for qi = 2*qig+1 (cols g=2,3)
    float tmax[4] = {-FLT_MAX, -FLT_MAX, -FLT_MAX, -FLT_MAX};
#pragma unroll
    for (int sh = 0; sh < 2; ++sh) {
        float smA[16], smB[16];
#pragma unroll
        for (int r = 0; r < 16; ++r) {
            int srow = sh * 32 + (r & 3) + 8 * (r >> 2) + 4 * h;
            float s0 = sigl[srow * 64 + c];
            float s1 = sigl[srow * 64 + 32 + c];
            float v0 = acc[sh][0][r] * s0;
            float v1 = acc[sh][1][r] * s1;
            float v2 = acc[sh][2][r] * s0;
            float v3 = acc[sh][3][r] * s1;
            tmax[0] = fmaxf(tmax[0], v0);
            tmax[1] = fmaxf(tmax[1], v1);
            tmax[2] = fmaxf(tmax[2], v2);
            tmax[3] = fmaxf(tmax[3], v3);
            smA[r] = fmaxf(v0, v1);
            smB[r] = fmaxf(v2, v3);
        }
#pragma unroll
        for (int stage = 1; stage < 32; stage <<= 1)
#pragma unroll
            for (int r = 0; r < 16; ++r) {
                smA[r] = fmaxf(smA[r], __shfl_xor(smA[r], stage, 64));
                smB[r] = fmaxf(smB[r], __shfl_xor(smB[r], stage, 64));
            }
        if (c == 0) {
#pragma unroll
            for (int r = 0; r < 16; ++r) {
                int srow = sh * 32 + (r & 3) + 8 * (r >> 2) + 4 * h;
                xbuf[(size_t)(2 * p0 + 1) * 64 + srow] = smA[r];
                xbuf[(size_t)(2 * p1 + 1) * 64 + srow] = smB[r];
            }
        }
    }
#pragma unroll
    for (int g = 0; g < 4; ++g)
        tmax[g] = fmaxf(tmax[g], __shfl_xor(tmax[g], 32, 64));
    if (h == 0) {
        xbuf[(size_t)(2 * p0) * 64 + c] = tmax[0];
        xbuf[(size_t)(2 * p0) * 64 + 32 + c] = tmax[1];
        xbuf[(size_t)(2 * p1) * 64 + c] = tmax[2];
        xbuf[(size_t)(2 * p1) * 64 + 32 + c] = tmax[3];
    }
}

// ---------------- K3: row stats partials (NO atomics) ----------------------
__global__ __launch_bounds__(256) void k_stats1(const float* __restrict__ xbuf,
        float* __restrict__ S1p, float* __restrict__ S2p) {
    __shared__ float xr[8][64];   // 2 KB
    int tid = threadIdx.x;
    int row0 = blockIdx.x * 128;
    float acc[16] = {};
    float s1 = 0.f;
    int a = tid >> 2;             // constant per thread
    int bbase = (tid & 3) * 16;
    int lr = tid >> 5, lc = (tid & 31) * 2;
    for (int it = 0; it < 16; ++it) {
        int r = row0 + it * 8;
        *reinterpret_cast<float2*>(&xr[lr][lc]) =
            *reinterpret_cast<const float2*>(&xbuf[(size_t)(r + lr) * 64 + lc]);
        __syncthreads();
        float xa[8];
#pragma unroll
        for (int j = 0; j < 8; ++j) xa[j] = xr[j][a];
#pragma unroll
        for (int j = 0; j < 8; ++j) {
            const float4* pb = reinterpret_cast<const float4*>(&xr[j][bbase]);
            float4 b0 = pb[0], b1 = pb[1], b2 = pb[2], b3 = pb[3];
            acc[0] += xa[j] * b0.x;  acc[1] += xa[j] * b0.y;
            acc[2] += xa[j] * b0.z;  acc[3] += xa[j] * b0.w;
            acc[4] += xa[j] * b1.x;  acc[5] += xa[j] * b1.y;
            acc[6] += xa[j] * b1.z;  acc[7] += xa[j] * b1.w;
            acc[8] += xa[j] * b2.x;  acc[9] += xa[j] * b2.y;
            acc[10] += xa[j] * b2.z; acc[11] += xa[j] * b2.w;
            acc[12] += xa[j] * b3.x; acc[13] += xa[j] * b3.y;
            acc[14] += xa[j] * b3.z; acc[15] += xa[j] * b3.w;
        }
        if (tid < 64) {
#pragma unroll
            for (int j = 0; j < 8; ++j) s1 += xr[j][tid];
        }
        __syncthreads();
    }
    float* dst = S2p + (size_t)blockIdx.x * 4096 + tid * 16;
#pragma unroll
    for (int e = 0; e < 16; e += 4)
        *reinterpret_cast<float4*>(dst + e) = make_float4(acc[e], acc[e+1], acc[e+2], acc[e+3]);
    if (tid < 64) S1p[blockIdx.x * 64 + tid] = s1;
}

// ---------------- K3b: reduce partials -> S2f[4096], S1f[64] ---------------
__global__ __launch_bounds__(256) void k_red(const float* __restrict__ S1p,
        const float* __restrict__ S2p, float* __restrict__ S1f,
        float* __restrict__ S2f) {
    __shared__ double part[4][64];
    __shared__ double p1s[4][64];
    int tid = threadIdx.x;
    int il = tid & 63, bq = tid >> 6;
    int idx = blockIdx.x * 64 + il;
    const float* b2 = S2p + (size_t)(bq * 64) * 4096 + idx;
    double a0 = 0, a1 = 0, a2 = 0, a3 = 0, a4 = 0, a5 = 0, a6 = 0, a7 = 0;
    for (int b = 0; b < 64; b += 8) {
        a0 += (double)b2[(size_t)(b + 0) * 4096];
        a1 += (double)b2[(size_t)(b + 1) * 4096];
        a2 += (double)b2[(size_t)(b + 2) * 4096];
        a3 += (double)b2[(size_t)(b + 3) * 4096];
        a4 += (double)b2[(size_t)(b + 4) * 4096];
        a5 += (double)b2[(size_t)(b + 5) * 4096];
        a6 += (double)b2[(size_t)(b + 6) * 4096];
        a7 += (double)b2[(size_t)(b + 7) * 4096];
    }
    part[bq][il] = ((a0 + a1) + (a2 + a3)) + ((a4 + a5) + (a6 + a7));
    if (blockIdx.x == 0) {
        const float* b1p = S1p + (size_t)(bq * 64) * 64 + il;
        double c0 = 0, c1 = 0, c2 = 0, c3 = 0;
        for (int b = 0; b < 64; b += 4) {
            c0 += (double)b1p[(size_t)(b + 0) * 64];
            c1 += (double)b1p[(size_t)(b + 1) * 64];
            c2 += (double)b1p[(size_t)(b + 2) * 64];
            c3 += (double)b1p[(size_t)(b + 3) * 64];
        }
        p1s[bq][il] = (c0 + c1) + (c2 + c3);
    }
    __syncthreads();
    if (tid < 64) {
        S2f[blockIdx.x * 64 + tid] =
            (float)(part[0][tid] + part[1][tid] + part[2][tid] + part[3][tid]);
        if (blockIdx.x == 0)
            S1f[tid] = (float)(p1s[0][tid] + p1s[1][tid] + p1s[2][tid] + p1s[3][tid]);
    }
}

// ---------------- K5: BN2 constants; BN1 stats inline; S2f in padded LDS ---
__global__ __launch_bounds__(256) void k_bn2(
        const float* __restrict__ S1f, const float* __restrict__ S2f,
        const __hip_bfloat16* __restrict__ W2b,
        const float* __restrict__ g1, const float* __restrict__ be1,
        const float* __restrict__ g2, const float* __restrict__ be2,
        float* __restrict__ alpha, float* __restrict__ beta) {
    __shared__ float S2c[64 * 65];
    __shared__ float mb[64];
    __shared__ float scal[3];   // sc2, m1, scaled
    int tid = threadIdx.x;
    const float Rinvf = 1.0f / (float)ROWSX;
#pragma unroll
    for (int i = 0; i < 16; ++i) {
        int idx = i * 256 + tid;
        S2c[(idx >> 6) * 65 + (idx & 63)] = S2f[idx];
    }
    if (tid < 64) {
        double ss = (double)S1f[tid];
        double sq = (double)S2f[tid * 65];
#pragma unroll
        for (int off = 32; off; off >>= 1) {
            ss += __shfl_down(ss, off);
            sq += __shfl_down(sq, off);
        }
        if (tid == 0) {
            const double Nall = (double)ROWSX * 64.0;
            double m1 = ss / Nall;
            double var1 = sq / Nall - m1 * m1;
            double scaled = (double)g1[0] / sqrt(var1 + 1e-5);
            scal[0] = (float)(scaled * scaled);
            scal[1] = (float)m1;
            scal[2] = (float)scaled;
        }
        mb[tid] = S1f[tid] * Rinvf;
    }
    __syncthreads();
    int w = tid >> 6;
    int j = tid & 63;
    int f = blockIdx.x * 4 + w;
    float wj = __bfloat162float(W2b[(size_t)f * 64 + j]);
    float mj = mb[j];
    float t1 = 0.f;
    for (int b = 0; b < 64; ++b)
        t1 += (S2c[j * 65 + b] * Rinvf - mj * mb[b]) * __bfloat162float(W2b[(size_t)f * 64 + b]);
    float vc = wj * t1 * scal[0];
    float xbj = (mj - scal[1]) * scal[2] + be1[0];
    float mc = wj * xbj;
#pragma unroll
    for (int off = 32; off; off >>= 1) {
        vc += __shfl_down(vc, off);
        mc += __shfl_down(mc, off);
    }
    if (j == 0) {
        float t2 = g2[f] * rsqrtf(vc + 1e-5f);
        alpha[f] = t2;
        beta[f] = -t2 * mc + be2[f];
    }
}

// ---------------- K6: MFMA MLP; 4-way feature split for occupancy ----------
__global__ __launch_bounds__(256, 4) void k_mlp_mfma(
        const float* __restrict__ xbuf, const float* __restrict__ S1f,
        const float* __restrict__ S2f, const float* __restrict__ g1,
        const float* __restrict__ be1, const __hip_bfloat16* __restrict__ W2b,
        const float* __restrict__ alpha, const float* __restrict__ beta,
        const float* __restrict__ W3, const float* __restrict__ b3,
        float* __restrict__ z4) {
    constexpr int LDR = 72;
    __shared__ __attribute__((aligned(16))) unsigned short Xs[128 * LDR];
    __shared__ __attribute__((aligned(16))) unsigned short Ws[128 * LDR];
    __shared__ float abw[3 * 128];
    __shared__ float scl[2];
    const unsigned short* W2u = reinterpret_cast<const unsigned short*>(W2b);
    int tid = threadIdx.x;
    int w = tid >> 6, l = tid & 63, h = l >> 5, c = l & 31;
    int rb = blockIdx.x >> 2, q = blockIdx.x & 3;
    int r0 = rb * 128;

    if (tid < 64) {
        double ss = (double)S1f[tid];
        double sq = (double)S2f[tid * 65];
#pragma unroll
        for (int off = 32; off; off >>= 1) {
            ss += __shfl_down(ss, off);
            sq += __shfl_down(sq, off);
        }
        if (tid == 0) {
            const double Nall = (double)ROWSX * 64.0;
            double m1 = ss / Nall;
            double var1 = sq / Nall - m1 * m1;
            scl[0] = (float)m1;
            scl[1] = (float)((double)g1[0] / sqrt(var1 + 1e-5));
        }
    }
    __syncthreads();
    float m1 = scl[0], sc = scl[1], sh = be1[0];

#pragma unroll
    for (int i = 0; i < 4; ++i) {
        int id = i * 256 + tid;
        int row = id >> 3, cg = id & 7;
        const float* src = xbuf + (size_t)(r0 + row) * 64 + cg * 8;
        float4 v0 = *reinterpret_cast<const float4*>(src);
        float4 v1 = *reinterpret_cast<const float4*>(src + 4);
        union { __hip_bfloat16 hh[8]; uint4 u; } o;
        o.hh[0] = __float2bfloat16((v0.x - m1) * sc + sh);
        o.hh[1] = __float2bfloat16((v0.y - m1) * sc + sh);
        o.hh[2] = __float2bfloat16((v0.z - m1) * sc + sh);
        o.hh[3] = __float2bfloat16((v0.w - m1) * sc + sh);
        o.hh[4] = __float2bfloat16((v1.x - m1) * sc + sh);
        o.hh[5] = __float2bfloat16((v1.y - m1) * sc + sh);
        o.hh[6] = __float2bfloat16((v1.z - m1) * sc + sh);
        o.hh[7] = __float2bfloat16((v1.w - m1) * sc + sh);
        *reinterpret_cast<uint4*>(&Xs[row * LDR + cg * 8]) = o.u;
    }

    float zacc[16] = {};
    for (int fci = 0; fci < 4; ++fci) {
        int fc = q * 4 + fci;
#pragma unroll
        for (int i = 0; i < 4; ++i) {
            int id = i * 256 + tid;
            int row = id >> 3, cg = id & 7;
            uint4 v = *reinterpret_cast<const uint4*>(W2u + (size_t)(fc * 128 + row) * 64 + cg * 8);
            *reinterpret_cast<uint4*>(&Ws[row * LDR + cg * 8]) = v;
        }
        if (tid < 128) {
            int f = fc * 128 + tid;
            abw[tid] = alpha[f];
            abw[128 + tid] = beta[f];
            abw[256 + tid] = W3[f];
        }
        __syncthreads();
        bf16x8 a[4];
#pragma unroll
        for (int st = 0; st < 4; ++st)
            a[st] = *reinterpret_cast<const bf16x8*>(&Xs[(w * 32 + c) * LDR + st * 16 + h * 8]);
#pragma unroll
        for (int nq = 0; nq < 4; ++nq) {
            floatx16 u = {};
#pragma unroll
            for (int st = 0; st < 4; ++st) {
                bf16x8 b = *reinterpret_cast<const bf16x8*>(&Ws[(nq * 32 + c) * LDR + st * 16 + h * 8]);
                u = __builtin_amdgcn_mfma_f32_32x32x16_bf16(a[st], b, u, 0, 0, 0);
            }
            float al = abw[nq * 32 + c];
            float bt = abw[128 + nq * 32 + c];
            float w3 = abw[256 + nq * 32 + c];
#pragma unroll
            for (int r = 0; r < 16; ++r)
                zacc[r] += fmaxf(al * u[r] + bt, 0.f) * w3;
        }
        __syncthreads();
    }
#pragma unroll
    for (int stage = 1; stage < 32; stage <<= 1)
#pragma unroll
        for (int r = 0; r < 16; ++r)
            zacc[r] += __shfl_xor(zacc[r], stage, 64);
    if (c == 0) {
        float bb = (q == 0) ? b3[0] : 0.f;
#pragma unroll
        for (int r = 0; r < 16; ++r) {
            int row = r0 + w * 32 + (r & 3) + 8 * (r >> 2) + 4 * h;
            z4[(size_t)q * ROWSX + row] = zacc[r] + bb;
        }
    }
}

// ---------------- K7: pair-sum (4 partials) + BN3 stats --------------------
__global__ __launch_bounds__(256) void k_pair(const float* __restrict__ z4,
        float* __restrict__ v, double* __restrict__ sums3) {
    int i = blockIdx.x * 256 + threadIdx.x;
    float val = 0.f;
#pragma unroll
    for (int q = 0; q < 4; ++q)
        val += z4[(size_t)q * ROWSX + 2 * i] + z4[(size_t)q * ROWSX + 2 * i + 1];
    v[i] = val;
    float s = val, ss = val * val;
#pragma unroll
    for (int off = 32; off; off >>= 1) {
        s += __shfl_down(s, off);
        ss += __shfl_down(ss, off);
    }
    __shared__ float bs[4], bss[4];
    int lane = threadIdx.x & 63, w = threadIdx.x >> 6;
    if (lane == 0) { bs[w] = s; bss[w] = ss; }
    __syncthreads();
    if (threadIdx.x == 0) {
        atomicAdd(&sums3[0], (double)(bs[0] + bs[1] + bs[2] + bs[3]));
        atomicAdd(&sums3[1], (double)(bss[0] + bss[1] + bss[2] + bss[3]));
    }
}

// ---------------- K9: BN3 finalize + write output --------------------------
__global__ __launch_bounds__(256) void k_out(const float* __restrict__ v,
        const double* __restrict__ sums3, const float* __restrict__ g3,
        const float* __restrict__ be3, float* __restrict__ out) {
    double m = sums3[0] / (double)PAIRS;
    double var = sums3[1] / (double)PAIRS - m * m;
    float mm = (float)m;
    float inv = (float)((double)g3[0] / sqrt(var + 1e-5));
    int i = blockIdx.x * 256 + threadIdx.x;
    if (i < PAIRS) out[i] = (v[i] - mm) * inv + be3[0];
}

extern "C" void kernel_launch(void* const* d_in, const int* in_sizes, int n_in,
                              void* d_out, int out_size, void* d_ws, size_t ws_size,
                              hipStream_t stream) {
    (void)in_sizes; (void)n_in; (void)out_size; (void)ws_size;
    const float* tgt = (const float*)d_in[0];
    const float* mem = (const float*)d_in[1];
    const float* W1  = (const float*)d_in[2];
    const float* b1  = (const float*)d_in[3];
    const float* se  = (const float*)d_in[4];
    const float* W2  = (const float*)d_in[5];
    const float* b2  = (const float*)d_in[6];
    const float* W3  = (const float*)d_in[7];
    const float* b3  = (const float*)d_in[8];
    const float* g1  = (const float*)d_in[9];
    const float* be1 = (const float*)d_in[10];
    const float* g2  = (const float*)d_in[11];
    const float* be2 = (const float*)d_in[12];
    const float* g3  = (const float*)d_in[13];
    const float* be3 = (const float*)d_in[14];
    const int*  flag = (const int*)d_in[15];
    (void)b2;  // cancels analytically through BN2's mean-subtract
    float* out = (float*)d_out;

    char* ws = (char*)d_ws;
    size_t off = 0;
    auto alloc = [&](size_t bytes) -> void* {
        void* p = ws + off;
        off = (off + bytes + 255) & ~(size_t)255;
        return p;
    };
    float* sig   = (float*)alloc((size_t)SSZ * SSZ * 4);
    __hip_bfloat16* W1b = (__hip_bfloat16*)alloc((size_t)D * D * 2);    // 0.5 MB
    __hip_bfloat16* W2b = (__hip_bfloat16*)alloc((size_t)FF * 64 * 2);  // 0.25 MB
    __hip_bfloat16* QKf = (__hip_bfloat16*)alloc((size_t)NX * D * 2);   // 21 MB (fragment layout)
    float* xbuf  = (float*)alloc((size_t)ROWSX * 64 * 4);               // 8 MB
    float* z4    = (float*)alloc((size_t)4 * ROWSX * 4);                // 0.5 MB
    float* v     = (float*)alloc((size_t)PAIRS * 4);
    float* alpha = (float*)alloc((size_t)FF * 4);
    float* beta  = (float*)alloc((size_t)FF * 4);
    float* S1p   = (float*)alloc((size_t)SBLK * 64 * 4);
    float* S2p   = (float*)alloc((size_t)SBLK * 4096 * 4);   // 4 MB
    float* S1f   = (float*)alloc(64 * 4);
    float* S2f   = (float*)alloc(4096 * 4);
    size_t statsStart = off;
    double* sums3 = (double*)alloc(2 * 8);
    size_t statsEnd = off;

    hipMemsetAsync(ws + statsStart, 0, statsEnd - statsStart, stream);

    constexpr int CVT4 = (D * D + FF * 64 + SSZ * SSZ) / 4;
    k_cvt<<<(CVT4 + 255) / 256, 256, 0, stream>>>(W1, W2, se, flag, W1b, W2b, sig);
    k_gemm1_mfma<<<(NX / 128) * (D / 128), 256, 0, stream>>>(tgt, mem, W1b, b1, flag, QKf);
    k_score_mfma<<<(NQ / 2) * (NK / 8), 512, 0, stream>>>(QKf, sig, xbuf);
    k_stats1<<<SBLK, 256, 0, stream>>>(xbuf, S1p, S2p);
    k_red<<<64, 256, 0, stream>>>(S1p, S2p, S1f, S2f);
    k_bn2<<<FF / 4, 256, 0, stream>>>(S1f, S2f, W2b, g1, be1, g2, be2, alpha, beta);
    k_mlp_mfma<<<(ROWSX / 128) * 4, 256, 0, stream>>>(xbuf, S1f, S2f, g1, be1, W2b,
                                                      alpha, beta, W3, b3, z4);
    k_pair<<<PAIRS / 256, 256, 0, stream>>>(z4, v, sums3);
    k_out<<<PAIRS / 256, 256, 0, stream>>>(v, sums3, g3, be3, out);
}

// Round 14
// 260.029 us; speedup vs baseline: 1.1304x; 1.0842x over previous
//
#include <hip/hip_runtime.h>
#include <hip/hip_bf16.h>
#include <math.h>
#include <float.h>

// dims
constexpr int NQ = 64, NK = 256, SSZ = 64, D = 512, FF = 2048;
constexpr int PAIRS = NQ * NK;          // 16384
constexpr int ROWSX = 2 * PAIRS;        // 32768
constexpr int NX = (NQ + NK) * SSZ;     // 20480 rows of X = [tgt;mem]
constexpr int SBLK = 256;               // stats1 partial blocks (full chip)

typedef __bf16 bf16x8 __attribute__((ext_vector_type(8)));
typedef float floatx16 __attribute__((ext_vector_type(16)));

// async global->LDS, 16 B per lane; LDS dest = wave-uniform base + lane*16
__device__ __forceinline__ void gl2lds16(const unsigned short* g, unsigned short* l) {
    __builtin_amdgcn_global_load_lds(
        (const __attribute__((address_space(1))) unsigned int*)(g),
        (__attribute__((address_space(3))) unsigned int*)(l),
        16, 0, 0);
}

// Fragment layout for QKf: block (rg, kgrp) = 1 KB at ((rg*32 + kgrp)*1024):
//   lane l (16 B entry at l*16) holds row rg*32 + (l&31),
//   k elems kgrp*16 + (l>>5)*8 .. +7  == exactly the 32x32x16 A/B fragment.

// ---------------- K0: convert X/W1/W2 to bf16 + sigmoid(score_embed) -------
__global__ __launch_bounds__(256) void k_cvt(
        const float* __restrict__ tgt, const float* __restrict__ mem,
        const float* __restrict__ W1, const float* __restrict__ W2,
        const float* __restrict__ se, const int* __restrict__ flag,
        __hip_bfloat16* __restrict__ Xb, __hip_bfloat16* __restrict__ W1b,
        __hip_bfloat16* __restrict__ W2b, float* __restrict__ sig) {
    constexpr int T4 = NQ * SSZ * D / 4;   // tgt float4 count
    constexpr int X4 = NX * D / 4;         // X float4 count
    constexpr int W4 = D * D / 4;          // W1 float4 count
    constexpr int V4 = FF * 64 / 4;        // W2 float4 count
    constexpr int S4 = SSZ * SSZ / 4;      // sig float4 count
    int idx = blockIdx.x * 256 + threadIdx.x;
    if (idx >= X4 + W4 + V4 + S4) return;
    if (idx >= X4 + W4 + V4) {             // sigmoid branch
        int s = (idx - X4 - W4 - V4) * 4;
        float4 v = *reinterpret_cast<const float4*>(se + s);
        bool fl = (*flag) != 0;
        float4 o;
        o.x = fl ? 1.0f / (1.0f + expf(-v.x)) : 1.0f;
        o.y = fl ? 1.0f / (1.0f + expf(-v.y)) : 1.0f;
        o.z = fl ? 1.0f / (1.0f + expf(-v.z)) : 1.0f;
        o.w = fl ? 1.0f / (1.0f + expf(-v.w)) : 1.0f;
        *reinterpret_cast<float4*>(sig + s) = o;
        return;
    }
    const float* src;
    __hip_bfloat16* dst;
    if (idx < T4)           { src = tgt + (size_t)idx * 4;             dst = Xb + (size_t)idx * 4; }
    else if (idx < X4)      { src = mem + (size_t)(idx - T4) * 4;      dst = Xb + (size_t)idx * 4; }
    else if (idx < X4 + W4) { src = W1 + (size_t)(idx - X4) * 4;       dst = W1b + (size_t)(idx - X4) * 4; }
    else                    { src = W2 + (size_t)(idx - X4 - W4) * 4;  dst = W2b + (size_t)(idx - X4 - W4) * 4; }
    float4 v = *reinterpret_cast<const float4*>(src);
    union { __hip_bfloat16 h[4]; uint2 u; } o;
    o.h[0] = __float2bfloat16(v.x); o.h[1] = __float2bfloat16(v.y);
    o.h[2] = __float2bfloat16(v.z); o.h[3] = __float2bfloat16(v.w);
    *reinterpret_cast<uint2*>(dst) = o.u;
}

// ---------------- K1: MFMA GEMM1: QKf = frag(Xb @ W1b^T + b1) --------------
__global__ __launch_bounds__(256, 3) void k_gemm1_mfma(
        const __hip_bfloat16* __restrict__ Xb, const __hip_bfloat16* __restrict__ W1b,
        const float* __restrict__ b1, const int* __restrict__ flag,
        __hip_bfloat16* __restrict__ QKf) {
    __shared__ __attribute__((aligned(16))) unsigned short lds[2 * 128 * 64]; // 32 KB
    const unsigned short* Xu = reinterpret_cast<const unsigned short*>(Xb);
    const unsigned short* Wu = reinterpret_cast<const unsigned short*>(W1b);
    unsigned short* Fu = reinterpret_cast<unsigned short*>(QKf);

    int tid = threadIdx.x;
    int bm = blockIdx.x >> 2, bn = blockIdx.x & 3;
    int m0 = bm * 128, n0 = bn * 128;

    if (!(*flag)) {
        // copy X rows into fragment layout (correctness path, flag==0 only)
#pragma unroll
        for (int i = 0; i < 8; ++i) {
            int e = i * 256 + tid;          // 0..2047 entries of 16 B
            int fb = e >> 6;                // frag block 0..31
            int lp = e & 63;                // lane entry
            int rgl = fb >> 3, kgl = fb & 7;
            int row = m0 + rgl * 32 + (lp & 31);
            int col = n0 + kgl * 16 + (lp >> 5) * 8;
            uint4 v = *reinterpret_cast<const uint4*>(Xu + (size_t)row * D + col);
            size_t ofs = ((size_t)((m0 >> 5) + rgl) * 32 + (n0 >> 4) + kgl) * 512 + lp * 8;
            *reinterpret_cast<uint4*>(Fu + ofs) = v;
        }
        return;
    }

    int w = tid >> 6, l = tid & 63, h = l >> 5, c = l & 31;
    int wm = w >> 1, wn = w & 1;
    int chg = (l & 7) ^ (l >> 3);     // swizzled source chunk for this lane
    int cx = c & 7;
    floatx16 acc00 = {}, acc01 = {}, acc10 = {}, acc11 = {};

    for (int kb = 0; kb < D; kb += 64) {
#pragma unroll
        for (int j = 0; j < 8; ++j) {
            int i = w * 8 + j;              // 0..31
            int buf = i >> 4;               // 0: A(X), 1: B(W1)
            int rb = (i & 15) * 8;
            int r = rb + (l >> 3);
            const unsigned short* src = (buf == 0)
                ? (Xu + (size_t)(m0 + r) * D + kb + chg * 8)
                : (Wu + (size_t)(n0 + r) * D + kb + chg * 8);
            gl2lds16(src, lds + buf * 8192 + rb * 64);
        }
        __syncthreads();
        const unsigned short* pA = lds + (wm * 64) * 64;
        const unsigned short* pB = lds + 8192 + (wn * 64) * 64;
#pragma unroll
        for (int st = 0; st < 4; ++st) {
            int ko = ((st * 2 + h) ^ cx) * 8;
            bf16x8 a0 = *reinterpret_cast<const bf16x8*>(pA + c * 64 + ko);
            bf16x8 a1 = *reinterpret_cast<const bf16x8*>(pA + (32 + c) * 64 + ko);
            bf16x8 b0 = *reinterpret_cast<const bf16x8*>(pB + c * 64 + ko);
            bf16x8 b1v = *reinterpret_cast<const bf16x8*>(pB + (32 + c) * 64 + ko);
            acc00 = __builtin_amdgcn_mfma_f32_32x32x16_bf16(b0, a0, acc00, 0, 0, 0);
            acc01 = __builtin_amdgcn_mfma_f32_32x32x16_bf16(b0, a1, acc01, 0, 0, 0);
            acc10 = __builtin_amdgcn_mfma_f32_32x32x16_bf16(b1v, a0, acc10, 0, 0, 0);
            acc11 = __builtin_amdgcn_mfma_f32_32x32x16_bf16(b1v, a1, acc11, 0, 0, 0);
        }
        __syncthreads();
    }

#pragma unroll
    for (int ni = 0; ni < 2; ++ni) {
        int nb = n0 + wn * 64 + ni * 32;
#pragma unroll
        for (int mi = 0; mi < 2; ++mi) {
            const floatx16& A = ni ? (mi ? acc11 : acc10) : (mi ? acc01 : acc00);
            int mb = m0 + wm * 64 + mi * 32;
            size_t rgbase = ((size_t)(mb >> 5) * 32 + (nb >> 4)) * 512;
#pragma unroll
            for (int g = 0; g < 4; ++g) {
                float4 bia = *reinterpret_cast<const float4*>(&b1[nb + 8 * g + 4 * h]);
                union { __hip_bfloat16 hh[4]; uint2 u; } o;
                o.hh[0] = __float2bfloat16(A[4 * g + 0] + bia.x);
                o.hh[1] = __float2bfloat16(A[4 * g + 1] + bia.y);
                o.hh[2] = __float2bfloat16(A[4 * g + 2] + bia.z);
                o.hh[3] = __float2bfloat16(A[4 * g + 3] + bia.w);
                *reinterpret_cast<uint2*>(Fu + rgbase + (size_t)(g >> 1) * 512
                                          + (c + 32 * (g & 1)) * 8 + 4 * h) = o.u;
            }
        }
    }
}

// ---------------- K2: MFMA score einsum + sigmoid + dual max ---------------
__global__ __launch_bounds__(512, 2) void k_score_mfma(
        const __hip_bfloat16* __restrict__ QKf, const float* __restrict__ sig,
        float* __restrict__ xbuf) {
    __shared__ __attribute__((aligned(16))) unsigned short lds[65536]; // 128KB Q
    const unsigned short* Fu = reinterpret_cast<const unsigned short*>(QKf);

    int tid = threadIdx.x;
    int w = tid >> 6, l = tid & 63, h = l >> 5, c = l & 31;
    int qig = blockIdx.x >> 5, ktg = blockIdx.x & 31;  // bid%8 = ktg%8 -> XCD-pinned K
    int kt = ktg * 8 + w;

    const unsigned short* Qg = Fu + (size_t)qig * 65536;
#pragma unroll
    for (int i = 0; i < 16; ++i) {
        int e = i * 512 + tid;          // 16-B entry index
        gl2lds16(Qg + e * 8, lds + e * 8);
    }

    const unsigned short* pK0 = Fu + (size_t)(128 + kt * 2) * 16384 + l * 8;
    const unsigned short* pK1 = pK0 + 16384;

    floatx16 acc[2][4] = {};
    bf16x8 ka0[2][4], ka1[2][4];     // [buf][st], rows sh=0 / sh=1
#pragma unroll
    for (int st = 0; st < 4; ++st) {
        ka0[0][st] = *reinterpret_cast<const bf16x8*>(pK0 + st * 512);
        ka1[0][st] = *reinterpret_cast<const bf16x8*>(pK1 + st * 512);
    }
    __syncthreads();   // Q staged (vmcnt drained); K step-0 complete

    const unsigned short* qlds = lds + l * 8;
#pragma unroll
    for (int kbi = 0; kbi < 8; ++kbi) {
        const int cur = kbi & 1, nxt = cur ^ 1;
        if (kbi < 7) {
            pK0 += 2048; pK1 += 2048;
#pragma unroll
            for (int st = 0; st < 4; ++st) {
                ka0[nxt][st] = *reinterpret_cast<const bf16x8*>(pK0 + st * 512);
                ka1[nxt][st] = *reinterpret_cast<const bf16x8*>(pK1 + st * 512);
            }
        }
#pragma unroll
        for (int g = 0; g < 4; ++g) {
            bf16x8 qb[4];
#pragma unroll
            for (int st = 0; st < 4; ++st)
                qb[st] = *reinterpret_cast<const bf16x8*>(qlds + (g * 32 + kbi * 4 + st) * 512);
            __builtin_amdgcn_s_setprio(1);
#pragma unroll
            for (int st = 0; st < 4; ++st) {
                acc[0][g] = __builtin_amdgcn_mfma_f32_32x32x16_bf16(ka0[cur][st], qb[st], acc[0][g], 0, 0, 0);
                acc[1][g] = __builtin_amdgcn_mfma_f32_32x32x16_bf16(ka1[cur][st], qb[st], acc[1][g], 0, 0, 0);
            }
            __builtin_amdgcn_s_setprio(0);
        }
    }

    const float* sigl = sig;   // 16 KB, L2/L1-hot, coalesced per-row reads

    int p0 = (qig * 2) * 256 + kt;   // pair for qi = 2*qig   (cols g=0,1)
    int p1 = p0 + 256;               // pair for qi = 2*qig+1 (cols g=2,3)
    float tmax[4] = {-FLT_MAX, -FLT_MAX, -FLT_MAX, -FLT_MAX};
#pragma unroll
    for (int sh = 0; sh < 2; ++sh) {
        float smA[16], smB[16];
#pragma unroll
        for (int r = 0; r < 16; ++r) {
            int srow = sh * 32 + (r & 3) + 8 * (r >> 2) + 4 * h;
            float s0 = sigl[srow * 64 + c];
            float s1 = sigl[srow * 64 + 32 + c];
            float v0 = acc[sh][0][r] * s0;
            float v1 = acc[sh][1][r] * s1;
            float v2 = acc[sh][2][r] * s0;
            float v3 = acc[sh][3][r] * s1;
            tmax[0] = fmaxf(tmax[0], v0);
            tmax[1] = fmaxf(tmax[1], v1);
            tmax[2] = fmaxf(tmax[2], v2);
            tmax[3] = fmaxf(tmax[3], v3);
            smA[r] = fmaxf(v0, v1);
            smB[r] = fmaxf(v2, v3);
        }
#pragma unroll
        for (int stage = 1; stage < 32; stage <<= 1)
#pragma unroll
            for (int r = 0; r < 16; ++r) {
                smA[r] = fmaxf(smA[r], __shfl_xor(smA[r], stage, 64));
                smB[r] = fmaxf(smB[r], __shfl_xor(smB[r], stage, 64));
            }
        if (c == 0) {
#pragma unroll
            for (int r = 0; r < 16; ++r) {
                int srow = sh * 32 + (r & 3) + 8 * (r >> 2) + 4 * h;
                xbuf[(size_t)(2 * p0 + 1) * 64 + srow] = smA[r];
                xbuf[(size_t)(2 * p1 + 1) * 64 + srow] = smB[r];
            }
        }
    }
#pragma unroll
    for (int g = 0; g < 4; ++g)
        tmax[g] = fmaxf(tmax[g], __shfl_xor(tmax[g], 32, 64));
    if (h == 0) {
        xbuf[(size_t)(2 * p0) * 64 + c] = tmax[0];
        xbuf[(size_t)(2 * p0) * 64 + 32 + c] = tmax[1];
        xbuf[(size_t)(2 * p1) * 64 + c] = tmax[2];
        xbuf[(size_t)(2 * p1) * 64 + 32 + c] = tmax[3];
    }
}

// ---------------- K3: row stats partials (NO atomics) ----------------------
__global__ __launch_bounds__(256) void k_stats1(const float* __restrict__ xbuf,
        float* __restrict__ S1p, float* __restrict__ S2p) {
    __shared__ float xr[8][64];   // 2 KB
    int tid = threadIdx.x;
    int row0 = blockIdx.x * 128;
    float acc[16] = {};
    float s1 = 0.f;
    int a = tid >> 2;             // constant per thread
    int bbase = (tid & 3) * 16;
    int lr = tid >> 5, lc = (tid & 31) * 2;
    for (int it = 0; it < 16; ++it) {
        int r = row0 + it * 8;
        *reinterpret_cast<float2*>(&xr[lr][lc]) =
            *reinterpret_cast<const float2*>(&xbuf[(size_t)(r + lr) * 64 + lc]);
        __syncthreads();
        float xa[8];
#pragma unroll
        for (int j = 0; j < 8; ++j) xa[j] = xr[j][a];
#pragma unroll
        for (int j = 0; j < 8; ++j) {
            const float4* pb = reinterpret_cast<const float4*>(&xr[j][bbase]);
            float4 b0 = pb[0], b1 = pb[1], b2 = pb[2], b3 = pb[3];
            acc[0] += xa[j] * b0.x;  acc[1] += xa[j] * b0.y;
            acc[2] += xa[j] * b0.z;  acc[3] += xa[j] * b0.w;
            acc[4] += xa[j] * b1.x;  acc[5] += xa[j] * b1.y;
            acc[6] += xa[j] * b1.z;  acc[7] += xa[j] * b1.w;
            acc[8] += xa[j] * b2.x;  acc[9] += xa[j] * b2.y;
            acc[10] += xa[j] * b2.z; acc[11] += xa[j] * b2.w;
            acc[12] += xa[j] * b3.x; acc[13] += xa[j] * b3.y;
            acc[14] += xa[j] * b3.z; acc[15] += xa[j] * b3.w;
        }
        if (tid < 64) {
#pragma unroll
            for (int j = 0; j < 8; ++j) s1 += xr[j][tid];
        }
        __syncthreads();
    }
    float* dst = S2p + (size_t)blockIdx.x * 4096 + tid * 16;
#pragma unroll
    for (int e = 0; e < 16; e += 4)
        *reinterpret_cast<float4*>(dst + e) = make_float4(acc[e], acc[e+1], acc[e+2], acc[e+3]);
    if (tid < 64) S1p[blockIdx.x * 64 + tid] = s1;
}

// ---------------- K3b: reduce partials -> S2f[4096], S1f[64] ---------------
__global__ __launch_bounds__(256) void k_red(const float* __restrict__ S1p,
        const float* __restrict__ S2p, float* __restrict__ S1f,
        float* __restrict__ S2f) {
    __shared__ double part[4][64];
    __shared__ double p1s[4][64];
    int tid = threadIdx.x;
    int il = tid & 63, bq = tid >> 6;
    int idx = blockIdx.x * 64 + il;
    const float* b2 = S2p + (size_t)(bq * 64) * 4096 + idx;
    double a0 = 0, a1 = 0, a2 = 0, a3 = 0, a4 = 0, a5 = 0, a6 = 0, a7 = 0;
    for (int b = 0; b < 64; b += 8) {
        a0 += (double)b2[(size_t)(b + 0) * 4096];
        a1 += (double)b2[(size_t)(b + 1) * 4096];
        a2 += (double)b2[(size_t)(b + 2) * 4096];
        a3 += (double)b2[(size_t)(b + 3) * 4096];
        a4 += (double)b2[(size_t)(b + 4) * 4096];
        a5 += (double)b2[(size_t)(b + 5) * 4096];
        a6 += (double)b2[(size_t)(b + 6) * 4096];
        a7 += (double)b2[(size_t)(b + 7) * 4096];
    }
    part[bq][il] = ((a0 + a1) + (a2 + a3)) + ((a4 + a5) + (a6 + a7));
    if (blockIdx.x == 0) {
        const float* b1p = S1p + (size_t)(bq * 64) * 64 + il;
        double c0 = 0, c1 = 0, c2 = 0, c3 = 0;
        for (int b = 0; b < 64; b += 4) {
            c0 += (double)b1p[(size_t)(b + 0) * 64];
            c1 += (double)b1p[(size_t)(b + 1) * 64];
            c2 += (double)b1p[(size_t)(b + 2) * 64];
            c3 += (double)b1p[(size_t)(b + 3) * 64];
        }
        p1s[bq][il] = (c0 + c1) + (c2 + c3);
    }
    __syncthreads();
    if (tid < 64) {
        S2f[blockIdx.x * 64 + tid] =
            (float)(part[0][tid] + part[1][tid] + part[2][tid] + part[3][tid]);
        if (blockIdx.x == 0)
            S1f[tid] = (float)(p1s[0][tid] + p1s[1][tid] + p1s[2][tid] + p1s[3][tid]);
    }
}

// ---------------- K5: BN2 constants; BN1 stats inline; S2f in padded LDS ---
__global__ __launch_bounds__(256) void k_bn2(
        const float* __restrict__ S1f, const float* __restrict__ S2f,
        const __hip_bfloat16* __restrict__ W2b,
        const float* __restrict__ g1, const float* __restrict__ be1,
        const float* __restrict__ g2, const float* __restrict__ be2,
        float* __restrict__ alpha, float* __restrict__ beta) {
    __shared__ float S2c[64 * 65];
    __shared__ float mb[64];
    __shared__ float scal[3];   // sc2, m1, scaled
    int tid = threadIdx.x;
    const float Rinvf = 1.0f / (float)ROWSX;
#pragma unroll
    for (int i = 0; i < 16; ++i) {
        int idx = i * 256 + tid;
        S2c[(idx >> 6) * 65 + (idx & 63)] = S2f[idx];
    }
    if (tid < 64) {
        double ss = (double)S1f[tid];
        double sq = (double)S2f[tid * 65];
#pragma unroll
        for (int off = 32; off; off >>= 1) {
            ss += __shfl_down(ss, off);
            sq += __shfl_down(sq, off);
        }
        if (tid == 0) {
            const double Nall = (double)ROWSX * 64.0;
            double m1 = ss / Nall;
            double var1 = sq / Nall - m1 * m1;
            double scaled = (double)g1[0] / sqrt(var1 + 1e-5);
            scal[0] = (float)(scaled * scaled);
            scal[1] = (float)m1;
            scal[2] = (float)scaled;
        }
        mb[tid] = S1f[tid] * Rinvf;
    }
    __syncthreads();
    int w = tid >> 6;
    int j = tid & 63;
    int f = blockIdx.x * 4 + w;
    float wj = __bfloat162float(W2b[(size_t)f * 64 + j]);
    float mj = mb[j];
    float t1 = 0.f;
    for (int b = 0; b < 64; ++b)
        t1 += (S2c[j * 65 + b] * Rinvf - mj * mb[b]) * __bfloat162float(W2b[(size_t)f * 64 + b]);
    float vc = wj * t1 * scal[0];
    float xbj = (mj - scal[1]) * scal[2] + be1[0];
    float mc = wj * xbj;
#pragma unroll
    for (int off = 32; off; off >>= 1) {
        vc += __shfl_down(vc, off);
        mc += __shfl_down(mc, off);
    }
    if (j == 0) {
        float t2 = g2[f] * rsqrtf(vc + 1e-5f);
        alpha[f] = t2;
        beta[f] = -t2 * mc + be2[f];
    }
}

// ---------------- K6: MFMA MLP; 4-way feature split for occupancy ----------
__global__ __launch_bounds__(256, 4) void k_mlp_mfma(
        const float* __restrict__ xbuf, const float* __restrict__ S1f,
        const float* __restrict__ S2f, const float* __restrict__ g1,
        const float* __restrict__ be1, const __hip_bfloat16* __restrict__ W2b,
        const float* __restrict__ alpha, const float* __restrict__ beta,
        const float* __restrict__ W3, const float* __restrict__ b3,
        float* __restrict__ z4) {
    constexpr int LDR = 72;
    __shared__ __attribute__((aligned(16))) unsigned short Xs[128 * LDR];
    __shared__ __attribute__((aligned(16))) unsigned short Ws[128 * LDR];
    __shared__ float abw[3 * 128];
    __shared__ float scl[2];
    const unsigned short* W2u = reinterpret_cast<const unsigned short*>(W2b);
    int tid = threadIdx.x;
    int w = tid >> 6, l = tid & 63, h = l >> 5, c = l & 31;
    int rb = blockIdx.x >> 2, q = blockIdx.x & 3;
    int r0 = rb * 128;

    if (tid < 64) {
        double ss = (double)S1f[tid];
        double sq = (double)S2f[tid * 65];
#pragma unroll
        for (int off = 32; off; off >>= 1) {
            ss += __shfl_down(ss, off);
            sq += __shfl_down(sq, off);
        }
        if (tid == 0) {
            const double Nall = (double)ROWSX * 64.0;
            double m1 = ss / Nall;
            double var1 = sq / Nall - m1 * m1;
            scl[0] = (float)m1;
            scl[1] = (float)((double)g1[0] / sqrt(var1 + 1e-5));
        }
    }
    __syncthreads();
    float m1 = scl[0], sc = scl[1], sh = be1[0];

#pragma unroll
    for (int i = 0; i < 4; ++i) {
        int id = i * 256 + tid;
        int row = id >> 3, cg = id & 7;
        const float* src = xbuf + (size_t)(r0 + row) * 64 + cg * 8;
        float4 v0 = *reinterpret_cast<const float4*>(src);
        float4 v1 = *reinterpret_cast<const float4*>(src + 4);
        union { __hip_bfloat16 hh[8]; uint4 u; } o;
        o.hh[0] = __float2bfloat16((v0.x - m1) * sc + sh);
        o.hh[1] = __float2bfloat16((v0.y - m1) * sc + sh);
        o.hh[2] = __float2bfloat16((v0.z - m1) * sc + sh);
        o.hh[3] = __float2bfloat16((v0.w - m1) * sc + sh);
        o.hh[4] = __float2bfloat16((v1.x - m1) * sc + sh);
        o.hh[5] = __float2bfloat16((v1.y - m1) * sc + sh);
        o.hh[6] = __float2bfloat16((v1.z - m1) * sc + sh);
        o.hh[7] = __float2bfloat16((v1.w - m1) * sc + sh);
        *reinterpret_cast<uint4*>(&Xs[row * LDR + cg * 8]) = o.u;
    }

    float zacc[16] = {};
    for (int fci = 0; fci < 4; ++fci) {
        int fc = q * 4 + fci;
#pragma unroll
        for (int i = 0; i < 4; ++i) {
            int id = i * 256 + tid;
            int row = id >> 3, cg = id & 7;
            uint4 v = *reinterpret_cast<const uint4*>(W2u + (size_t)(fc * 128 + row) * 64 + cg * 8);
            *reinterpret_cast<uint4*>(&Ws[row * LDR + cg * 8]) = v;
        }
        if (tid < 128) {
            int f = fc * 128 + tid;
            abw[tid] = alpha[f];
            abw[128 + tid] = beta[f];
            abw[256 + tid] = W3[f];
        }
        __syncthreads();
        bf16x8 a[4];
#pragma unroll
        for (int st = 0; st < 4; ++st)
            a[st] = *reinterpret_cast<const bf16x8*>(&Xs[(w * 32 + c) * LDR + st * 16 + h * 8]);
#pragma unroll
        for (int nq = 0; nq < 4; ++nq) {
            floatx16 u = {};
#pragma unroll
            for (int st = 0; st < 4; ++st) {
                bf16x8 b = *reinterpret_cast<const bf16x8*>(&Ws[(nq * 32 + c) * LDR + st * 16 + h * 8]);
                u = __builtin_amdgcn_mfma_f32_32x32x16_bf16(a[st], b, u, 0, 0, 0);
            }
            float al = abw[nq * 32 + c];
            float bt = abw[128 + nq * 32 + c];
            float w3 = abw[256 + nq * 32 + c];
#pragma unroll
            for (int r = 0; r < 16; ++r)
                zacc[r] += fmaxf(al * u[r] + bt, 0.f) * w3;
        }
        __syncthreads();
    }
#pragma unroll
    for (int stage = 1; stage < 32; stage <<= 1)
#pragma unroll
        for (int r = 0; r < 16; ++r)
            zacc[r] += __shfl_xor(zacc[r], stage, 64);
    if (c == 0) {
        float bb = (q == 0) ? b3[0] : 0.f;
#pragma unroll
        for (int r = 0; r < 16; ++r) {
            int row = r0 + w * 32 + (r & 3) + 8 * (r >> 2) + 4 * h;
            z4[(size_t)q * ROWSX + row] = zacc[r] + bb;
        }
    }
}

// ---------------- K7: pair-sum (4 partials) + BN3 stats --------------------
__global__ __launch_bounds__(256) void k_pair(const float* __restrict__ z4,
        float* __restrict__ v, double* __restrict__ sums3) {
    int i = blockIdx.x * 256 + threadIdx.x;
    float val = 0.f;
#pragma unroll
    for (int q = 0; q < 4; ++q)
        val += z4[(size_t)q * ROWSX + 2 * i] + z4[(size_t)q * ROWSX + 2 * i + 1];
    v[i] = val;
    float s = val, ss = val * val;
#pragma unroll
    for (int off = 32; off; off >>= 1) {
        s += __shfl_down(s, off);
        ss += __shfl_down(ss, off);
    }
    __shared__ float bs[4], bss[4];
    int lane = threadIdx.x & 63, w = threadIdx.x >> 6;
    if (lane == 0) { bs[w] = s; bss[w] = ss; }
    __syncthreads();
    if (threadIdx.x == 0) {
        atomicAdd(&sums3[0], (double)(bs[0] + bs[1] + bs[2] + bs[3]));
        atomicAdd(&sums3[1], (double)(bss[0] + bss[1] + bss[2] + bss[3]));
    }
}

// ---------------- K9: BN3 finalize + write output --------------------------
__global__ __launch_bounds__(256) void k_out(const float* __restrict__ v,
        const double* __restrict__ sums3, const float* __restrict__ g3,
        const float* __restrict__ be3, float* __restrict__ out) {
    double m = sums3[0] / (double)PAIRS;
    double var = sums3[1] / (double)PAIRS - m * m;
    float mm = (float)m;
    float inv = (float)((double)g3[0] / sqrt(var + 1e-5));
    int i = blockIdx.x * 256 + threadIdx.x;
    if (i < PAIRS) out[i] = (v[i] - mm) * inv + be3[0];
}

extern "C" void kernel_launch(void* const* d_in, const int* in_sizes, int n_in,
                              void* d_out, int out_size, void* d_ws, size_t ws_size,
                              hipStream_t stream) {
    (void)in_sizes; (void)n_in; (void)out_size; (void)ws_size;
    const float* tgt = (const float*)d_in[0];
    const float* mem = (const float*)d_in[1];
    const float* W1  = (const float*)d_in[2];
    const float* b1  = (const float*)d_in[3];
    const float* se  = (const float*)d_in[4];
    const float* W2  = (const float*)d_in[5];
    const float* b2  = (const float*)d_in[6];
    const float* W3  = (const float*)d_in[7];
    const float* b3  = (const float*)d_in[8];
    const float* g1  = (const float*)d_in[9];
    const float* be1 = (const float*)d_in[10];
    const float* g2  = (const float*)d_in[11];
    const float* be2 = (const float*)d_in[12];
    const float* g3  = (const float*)d_in[13];
    const float* be3 = (const float*)d_in[14];
    const int*  flag = (const int*)d_in[15];
    (void)b2;  // cancels analytically through BN2's mean-subtract
    float* out = (float*)d_out;

    char* ws = (char*)d_ws;
    size_t off = 0;
    auto alloc = [&](size_t bytes) -> void* {
        void* p = ws + off;
        off = (off + bytes + 255) & ~(size_t)255;
        return p;
    };
    float* sig   = (float*)alloc((size_t)SSZ * SSZ * 4);
    __hip_bfloat16* Xb  = (__hip_bfloat16*)alloc((size_t)NX * D * 2);   // 21 MB
    __hip_bfloat16* W1b = (__hip_bfloat16*)alloc((size_t)D * D * 2);    // 0.5 MB
    __hip_bfloat16* W2b = (__hip_bfloat16*)alloc((size_t)FF * 64 * 2);  // 0.25 MB
    __hip_bfloat16* QKf = (__hip_bfloat16*)alloc((size_t)NX * D * 2);   // 21 MB (fragment layout)
    float* xbuf  = (float*)alloc((size_t)ROWSX * 64 * 4);               // 8 MB
    float* z4    = (float*)alloc((size_t)4 * ROWSX * 4);                // 0.5 MB
    float* v     = (float*)alloc((size_t)PAIRS * 4);
    float* alpha = (float*)alloc((size_t)FF * 4);
    float* beta  = (float*)alloc((size_t)FF * 4);
    float* S1p   = (float*)alloc((size_t)SBLK * 64 * 4);
    float* S2p   = (float*)alloc((size_t)SBLK * 4096 * 4);   // 4 MB
    float* S1f   = (float*)alloc(64 * 4);
    float* S2f   = (float*)alloc(4096 * 4);
    size_t statsStart = off;
    double* sums3 = (double*)alloc(2 * 8);
    size_t statsEnd = off;

    hipMemsetAsync(ws + statsStart, 0, statsEnd - statsStart, stream);

    constexpr int CVT4 = (NX * D + D * D + FF * 64 + SSZ * SSZ) / 4;
    k_cvt<<<(CVT4 + 255) / 256, 256, 0, stream>>>(
        tgt, mem, W1, W2, se, flag, Xb, W1b, W2b, sig);
    k_gemm1_mfma<<<(NX / 128) * (D / 128), 256, 0, stream>>>(Xb, W1b, b1, flag, QKf);
    k_score_mfma<<<(NQ / 2) * (NK / 8), 512, 0, stream>>>(QKf, sig, xbuf);
    k_stats1<<<SBLK, 256, 0, stream>>>(xbuf, S1p, S2p);
    k_red<<<64, 256, 0, stream>>>(S1p, S2p, S1f, S2f);
    k_bn2<<<FF / 4, 256, 0, stream>>>(S1f, S2f, W2b, g1, be1, g2, be2, alpha, beta);
    k_mlp_mfma<<<(ROWSX / 128) * 4, 256, 0, stream>>>(xbuf, S1f, S2f, g1, be1, W2b,
                                                      alpha, beta, W3, b3, z4);
    k_pair<<<PAIRS / 256, 256, 0, stream>>>(z4, v, sums3);
    k_out<<<PAIRS / 256, 256, 0, stream>>>(v, sums3, g3, be3, out);
}